// Round 7
// baseline (718.156 us; speedup 1.0000x reference)
//
#include <hip/hip_runtime.h>
#include <math.h>

#define N_NODES 100000
#define H_DIM 64
#define G_GRAPHS 512
#define NEG_SLOPE 0.2f

// bucketed CSR-build params
#define BSHIFT 9                         // 512 nodes per bucket
#define NBKT ((N_NODES + (1 << BSHIFT) - 1) >> BSHIFT)   // 196
#define CHUNK_E 4096                     // edges per partition block (16/thread)

#define DEG_CAP 96                       // staged edges per node (multiple of 8; max obs deg ~45)

// ---------------------------------------------------------------------------
// CSR build, bucket-first: no per-edge global atomics anywhere.
// ---------------------------------------------------------------------------

// 196-bin LDS histogram -> 196 global atomics per block
__global__ __launch_bounds__(256) void bucket_hist_kernel(const int* __restrict__ dst,
                                                          int* __restrict__ bcount, int E) {
    __shared__ int lh[NBKT];
    int t = threadIdx.x;
    for (int i = t; i < NBKT; i += 256) lh[i] = 0;
    __syncthreads();
    int base = blockIdx.x * CHUNK_E;
#pragma unroll
    for (int k = 0; k < 16; ++k) {
        int e = base + k * 256 + t;
        if (e < E) atomicAdd(&lh[dst[e] >> BSHIFT], 1);
    }
    __syncthreads();
    for (int i = t; i < NBKT; i += 256) {
        int c = lh[i];
        if (c) atomicAdd(&bcount[i], c);
    }
}

// single block: exclusive scan of 196 bucket counts -> bbase[0..NBKT], bfill copy
__global__ __launch_bounds__(256) void bucket_scan_kernel(const int* __restrict__ bcount,
                                                          int* __restrict__ bbase,
                                                          int* __restrict__ bfill,
                                                          int* __restrict__ off, int n) {
    __shared__ int sm[256];
    int t = threadIdx.x;
    sm[t] = (t < NBKT) ? bcount[t] : 0;
    __syncthreads();
    for (int d = 1; d < 256; d <<= 1) {
        int v = (t >= d) ? sm[t - d] : 0;
        __syncthreads();
        sm[t] += v;
        __syncthreads();
    }
    if (t < NBKT) {
        int ex = (t == 0) ? 0 : sm[t - 1];
        bbase[t] = ex;
        bfill[t] = ex;
    }
    if (t == 0) {
        bbase[NBKT] = sm[255];       // = E
        off[n] = sm[255];
    }
}

// Radix-partition edges by dst bucket. LDS histogram -> one global atomicAdd
// per (block,bucket) -> LDS-rank -> writes are contiguous runs per bucket.
__global__ __launch_bounds__(256) void partition_kernel(const int* __restrict__ src,
                                                        const int* __restrict__ dst,
                                                        int* __restrict__ bfill,
                                                        int2* __restrict__ ebuck, int E) {
    __shared__ int lh[NBKT];
    __shared__ int lbase[NBKT];
    int t = threadIdx.x;
    int base = blockIdx.x * CHUNK_E;
    for (int i = t; i < NBKT; i += 256) lh[i] = 0;
    __syncthreads();

    int s[16], d[16], bk[16];
#pragma unroll
    for (int k = 0; k < 16; ++k) {
        int e = base + k * 256 + t;
        if (e < E) {
            s[k] = src[e];
            d[k] = dst[e];
            bk[k] = d[k] >> BSHIFT;
            atomicAdd(&lh[bk[k]], 1);
        } else {
            bk[k] = -1;
        }
    }
    __syncthreads();
    for (int i = t; i < NBKT; i += 256) {
        int c = lh[i];
        lbase[i] = c ? atomicAdd(&bfill[i], c) : 0;
        lh[i] = 0;
    }
    __syncthreads();
#pragma unroll
    for (int k = 0; k < 16; ++k) {
        if (bk[k] >= 0) {
            int r = atomicAdd(&lh[bk[k]], 1);
            ebuck[lbase[bk[k]] + r] = make_int2(s[k], d[k]);
        }
    }
}

// One block per bucket: LDS 512-bin node histogram -> LDS scan -> off[] write,
// then rank each edge via LDS atomicAdd and store esrc at its final CSR slot.
__global__ __launch_bounds__(256) void bucket_csr_kernel(const int2* __restrict__ ebuck,
                                                         const int* __restrict__ bbase,
                                                         int* __restrict__ off,
                                                         int* __restrict__ esrc, int n) {
    __shared__ int cnt[512];
    __shared__ int loff[512];
    __shared__ int sm[256];
    int b = blockIdx.x;
    int t = threadIdx.x;
    int ebeg = bbase[b];
    int eend = bbase[b + 1];
    int nbeg = b << BSHIFT;
    int nloc = n - nbeg; if (nloc > 512) nloc = 512;

    cnt[t] = 0; cnt[t + 256] = 0;
    __syncthreads();
    for (int e = ebeg + t; e < eend; e += 256) {
        atomicAdd(&cnt[ebuck[e].y - nbeg], 1);
    }
    __syncthreads();
    // exclusive scan of 512 counts (2 per thread)
    int c0 = cnt[2 * t], c1 = cnt[2 * t + 1];
    sm[t] = c0 + c1;
    __syncthreads();
    for (int d = 1; d < 256; d <<= 1) {
        int v = (t >= d) ? sm[t - d] : 0;
        __syncthreads();
        sm[t] += v;
        __syncthreads();
    }
    int basep = (t == 0) ? 0 : sm[t - 1];
    loff[2 * t] = basep;
    loff[2 * t + 1] = basep + c0;
    // reuse cnt as rank counters
    cnt[2 * t] = 0; cnt[2 * t + 1] = 0;
    __syncthreads();
    // write global off for this bucket's nodes
    for (int i = t; i < nloc; i += 256) off[nbeg + i] = ebeg + loff[i];
    // rank + final scatter (writes stay inside this bucket's esrc window)
    for (int e = ebeg + t; e < eend; e += 256) {
        int2 sd = ebuck[e];
        int d = sd.y - nbeg;
        int r = atomicAdd(&cnt[d], 1);
        esrc[ebeg + loff[d] + r] = sd.x;
    }
}

// ---------------------------------------------------------------------------
// GEMM + fused attention logits, v7: NO x LDS tile. Only W (16KB, zero-padded)
// stays in LDS -> 4 blocks/CU x 512 thr at <=64 VGPR = full occupancy.
// Thread (f4 = t&15, ng = t>>4 in [0,32)) computes 4 features x 4 rows.
// x chunks are group-uniform float4 global loads (one L1-served broadcast per
// row per k4; each x row is streamed exactly once chip-wide).
// ---------------------------------------------------------------------------
template <int FIN, int FINP>
__global__ __launch_bounds__(512, 8) void gemm_tile_kernel(
        const float* __restrict__ act, const float* __restrict__ W,
        const float* __restrict__ a_s, const float* __restrict__ a_d,
        float* __restrict__ h, float* __restrict__ ls, float* __restrict__ ld,
        int n) {
    __shared__ float sw[FINP * 64];
    int t = threadIdx.x;
    int tb = blockIdx.x * 128;
    int nrow = n - tb; if (nrow > 128) nrow = 128;

    // stage W, zero-padded for k in [FIN, FINP)
    {
        const float4* Wv = (const float4*)W;
        float4* swv = (float4*)sw;
        for (int i = t; i < FINP * 16; i += 512) {
            int k = i >> 4;
            swv[i] = (k < FIN) ? Wv[i] : make_float4(0.0f, 0.0f, 0.0f, 0.0f);
        }
    }
    __syncthreads();

    int f4 = t & 15;
    int ng = t >> 4;          // [0, 32)

    float4 acc[4];
#pragma unroll
    for (int i = 0; i < 4; ++i) acc[i] = make_float4(0.0f, 0.0f, 0.0f, 0.0f);

    // clamped row bases (rows >= nrow read row 0; results discarded on store)
    const float* xr[4];
#pragma unroll
    for (int i = 0; i < 4; ++i) {
        int r = ng + 32 * i;
        int rr = (r < nrow) ? r : 0;
        xr[i] = act + (size_t)(tb + rr) * FIN;
    }

    for (int k4 = 0; k4 < FINP; k4 += 4) {
        float4 w0 = *(const float4*)(sw + (k4 + 0) * 64 + f4 * 4);
        float4 w1 = *(const float4*)(sw + (k4 + 1) * 64 + f4 * 4);
        float4 w2 = *(const float4*)(sw + (k4 + 2) * 64 + f4 * 4);
        float4 w3 = *(const float4*)(sw + (k4 + 3) * 64 + f4 * 4);
#pragma unroll
        for (int i = 0; i < 4; ++i) {
            float4 xv;
            if (FIN == 14 && k4 == 12) {          // last chunk of a 14-float row
                float2 x2 = *(const float2*)(xr[i] + k4);
                xv = make_float4(x2.x, x2.y, 0.0f, 0.0f);
            } else {
                xv = *(const float4*)(xr[i] + k4);
            }
            acc[i].x = fmaf(xv.x, w0.x, acc[i].x);
            acc[i].y = fmaf(xv.x, w0.y, acc[i].y);
            acc[i].z = fmaf(xv.x, w0.z, acc[i].z);
            acc[i].w = fmaf(xv.x, w0.w, acc[i].w);
            acc[i].x = fmaf(xv.y, w1.x, acc[i].x);
            acc[i].y = fmaf(xv.y, w1.y, acc[i].y);
            acc[i].z = fmaf(xv.y, w1.z, acc[i].z);
            acc[i].w = fmaf(xv.y, w1.w, acc[i].w);
            acc[i].x = fmaf(xv.z, w2.x, acc[i].x);
            acc[i].y = fmaf(xv.z, w2.y, acc[i].y);
            acc[i].z = fmaf(xv.z, w2.z, acc[i].z);
            acc[i].w = fmaf(xv.z, w2.w, acc[i].w);
            acc[i].x = fmaf(xv.w, w3.x, acc[i].x);
            acc[i].y = fmaf(xv.w, w3.y, acc[i].y);
            acc[i].z = fmaf(xv.w, w3.z, acc[i].z);
            acc[i].w = fmaf(xv.w, w3.w, acc[i].w);
        }
    }

    float4 as4 = *(const float4*)(a_s + f4 * 4);
    float4 ad4 = *(const float4*)(a_d + f4 * 4);
#pragma unroll
    for (int i = 0; i < 4; ++i) {
        int r = ng + 32 * i;
        if (r < nrow) {                       // uniform within the 16-lane group
            int node = tb + r;
            *(float4*)(h + (size_t)node * 64 + f4 * 4) = acc[i];
            float vs = acc[i].x * as4.x + acc[i].y * as4.y +
                       acc[i].z * as4.z + acc[i].w * as4.w;
            float vd = acc[i].x * ad4.x + acc[i].y * ad4.y +
                       acc[i].z * ad4.z + acc[i].w * ad4.w;
            vs += __shfl_xor(vs, 1, 64); vd += __shfl_xor(vd, 1, 64);
            vs += __shfl_xor(vs, 2, 64); vd += __shfl_xor(vd, 2, 64);
            vs += __shfl_xor(vs, 4, 64); vd += __shfl_xor(vd, 4, 64);
            vs += __shfl_xor(vs, 8, 64); vd += __shfl_xor(vd, 8, 64);
            if (f4 == 0) { ls[node] = vs; ld[node] = vd; }
        }
    }
}

// ---------------------------------------------------------------------------
// GAT aggregation v5: round-5 structure (16-lane group per node, LDS-staged
// (src,p)), gather loop widened to 8-wide SINGLE-stage (8 independent row
// loads issued, then consumed; no double buffer). launch_bounds(256,8) pins
// VGPR <= 64 so occupancy stays at 8 blocks/CU (the v6 regression was 68
// VGPR -> waves halved).
// ---------------------------------------------------------------------------
__global__ __launch_bounds__(256, 8) void gat_aggregate_kernel(
        const float* __restrict__ h, const float* __restrict__ ls,
        const float* __restrict__ ld, const int* __restrict__ off,
        const int* __restrict__ esrc, const float* __restrict__ bias,
        float* __restrict__ hout, int n) {
    __shared__ int2 smq[16 * DEG_CAP];       // .x = src, .y = ls bits then p bits
    int t = threadIdx.x;
    int fl = t & 15;
    int g = t >> 4;
    int node = blockIdx.x * 16 + g;
    if (node >= n) return;
    int2* sq = smq + g * DEG_CAP;
    int fl4 = fl * 4;

    int jb = off[node];
    int je = off[node + 1];
    int deg = je - jb;
    int degc = (deg < DEG_CAP) ? deg : DEG_CAP;
    float ldv = ld[node];
    float lself = ls[node];

    // pass 1: gather ls, stage, running max of raw ls (leaky is monotone)
    float mm = lself;
    for (int c = fl; c < degc; c += 16) {
        int s = esrc[jb + c];
        float v = ls[s];
        sq[c] = make_int2(s, __float_as_int(v));
        mm = fmaxf(mm, v);
    }
    for (int c = degc + fl; c < deg; c += 16) {        // overflow: max only
        mm = fmaxf(mm, ls[esrc[jb + c]]);
    }
    mm = fmaxf(mm, __shfl_xor(mm, 8, 64));
    mm = fmaxf(mm, __shfl_xor(mm, 4, 64));
    mm = fmaxf(mm, __shfl_xor(mm, 2, 64));
    mm = fmaxf(mm, __shfl_xor(mm, 1, 64));
    float mraw = mm + ldv;
    float m = (mraw >= 0.0f) ? mraw : NEG_SLOPE * mraw;

    // pass 2: lsv -> p in LDS, lane-partial den
    float denl = 0.0f;
    for (int c = fl; c < degc; c += 16) {
        float e = __int_as_float(sq[c].y) + ldv;
        e = (e >= 0.0f) ? e : NEG_SLOPE * e;
        float p = __expf(e - m);
        sq[c].y = __float_as_int(p);
        denl += p;
    }
    // pad to multiple of 8 with (self, p=0): exact no-op, row is cache-hot
    int degc8 = (degc + 7) & ~7;
    if (fl < degc8 - degc) sq[degc + fl] = make_int2(node, 0);

    denl += __shfl_xor(denl, 8, 64);
    denl += __shfl_xor(denl, 4, 64);
    denl += __shfl_xor(denl, 2, 64);
    denl += __shfl_xor(denl, 1, 64);

    // gather loop: 8 independent 256B row loads in flight per group
    float4 acc = make_float4(0.0f, 0.0f, 0.0f, 0.0f);
    for (int c = 0; c < degc8; c += 8) {
        int2 e0 = sq[c + 0];
        int2 e1 = sq[c + 1];
        int2 e2 = sq[c + 2];
        int2 e3 = sq[c + 3];
        int2 e4 = sq[c + 4];
        int2 e5 = sq[c + 5];
        int2 e6 = sq[c + 6];
        int2 e7 = sq[c + 7];
        const float4 h0 = *(const float4*)(h + (size_t)e0.x * 64 + fl4);
        const float4 h1 = *(const float4*)(h + (size_t)e1.x * 64 + fl4);
        const float4 h2 = *(const float4*)(h + (size_t)e2.x * 64 + fl4);
        const float4 h3 = *(const float4*)(h + (size_t)e3.x * 64 + fl4);
        const float4 h4 = *(const float4*)(h + (size_t)e4.x * 64 + fl4);
        const float4 h5 = *(const float4*)(h + (size_t)e5.x * 64 + fl4);
        const float4 h6 = *(const float4*)(h + (size_t)e6.x * 64 + fl4);
        const float4 h7 = *(const float4*)(h + (size_t)e7.x * 64 + fl4);
        float p0 = __int_as_float(e0.y), p1 = __int_as_float(e1.y);
        float p2 = __int_as_float(e2.y), p3 = __int_as_float(e3.y);
        float p4 = __int_as_float(e4.y), p5 = __int_as_float(e5.y);
        float p6 = __int_as_float(e6.y), p7 = __int_as_float(e7.y);
        acc.x = fmaf(p0, h0.x, acc.x); acc.y = fmaf(p0, h0.y, acc.y);
        acc.z = fmaf(p0, h0.z, acc.z); acc.w = fmaf(p0, h0.w, acc.w);
        acc.x = fmaf(p1, h1.x, acc.x); acc.y = fmaf(p1, h1.y, acc.y);
        acc.z = fmaf(p1, h1.z, acc.z); acc.w = fmaf(p1, h1.w, acc.w);
        acc.x = fmaf(p2, h2.x, acc.x); acc.y = fmaf(p2, h2.y, acc.y);
        acc.z = fmaf(p2, h2.z, acc.z); acc.w = fmaf(p2, h2.w, acc.w);
        acc.x = fmaf(p3, h3.x, acc.x); acc.y = fmaf(p3, h3.y, acc.y);
        acc.z = fmaf(p3, h3.z, acc.z); acc.w = fmaf(p3, h3.w, acc.w);
        acc.x = fmaf(p4, h4.x, acc.x); acc.y = fmaf(p4, h4.y, acc.y);
        acc.z = fmaf(p4, h4.z, acc.z); acc.w = fmaf(p4, h4.w, acc.w);
        acc.x = fmaf(p5, h5.x, acc.x); acc.y = fmaf(p5, h5.y, acc.y);
        acc.z = fmaf(p5, h5.z, acc.z); acc.w = fmaf(p5, h5.w, acc.w);
        acc.x = fmaf(p6, h6.x, acc.x); acc.y = fmaf(p6, h6.y, acc.y);
        acc.z = fmaf(p6, h6.z, acc.z); acc.w = fmaf(p6, h6.w, acc.w);
        acc.x = fmaf(p7, h7.x, acc.x); acc.y = fmaf(p7, h7.y, acc.y);
        acc.z = fmaf(p7, h7.z, acc.z); acc.w = fmaf(p7, h7.w, acc.w);
    }

    // overflow tail (deg > DEG_CAP, ~never): serial, group-uniform den part
    float den_of = 0.0f;
    for (int j = jb + DEG_CAP; j < je; ++j) {
        int s = esrc[j];
        float e = ls[s] + ldv;
        e = (e >= 0.0f) ? e : NEG_SLOPE * e;
        float p = __expf(e - m);
        den_of += p;
        const float4 hv = *(const float4*)(h + (size_t)s * 64 + fl4);
        acc.x = fmaf(p, hv.x, acc.x);
        acc.y = fmaf(p, hv.y, acc.y);
        acc.z = fmaf(p, hv.z, acc.z);
        acc.w = fmaf(p, hv.w, acc.w);
    }

    // self loop
    const float4 hs = *(const float4*)(h + (size_t)node * 64 + fl4);
    float e0s = lself + ldv;
    e0s = (e0s >= 0.0f) ? e0s : NEG_SLOPE * e0s;
    float p0s = __expf(e0s - m);
    float den = denl + den_of + p0s;
    acc.x = fmaf(p0s, hs.x, acc.x);
    acc.y = fmaf(p0s, hs.y, acc.y);
    acc.z = fmaf(p0s, hs.z, acc.z);
    acc.w = fmaf(p0s, hs.w, acc.w);

    const float4 b4 = *(const float4*)(bias + fl4);
    float inv = 1.0f / den;
    float4 o;
    o.x = acc.x * inv + b4.x;
    o.y = acc.y * inv + b4.y;
    o.z = acc.z * inv + b4.z;
    o.w = acc.w * inv + b4.w;
    o.x = (o.x > 0.0f) ? o.x : expm1f(o.x);
    o.y = (o.y > 0.0f) ? o.y : expm1f(o.y);
    o.z = (o.z > 0.0f) ? o.z : expm1f(o.z);
    o.w = (o.w > 0.0f) ? o.w : expm1f(o.w);
    *(float4*)(hout + (size_t)node * 64 + fl4) = o;
}

// ---------------------------------------------------------------------------
// Global max pool: run-length (batch is sorted) + encoded atomicMax
// ---------------------------------------------------------------------------
__device__ __forceinline__ unsigned enc_f32(float f) {
    unsigned b = __float_as_uint(f);
    return (b & 0x80000000u) ? ~b : (b | 0x80000000u);
}

__global__ __launch_bounds__(256) void pool_kernel(const float* __restrict__ h,
                                                   const int* __restrict__ batch,
                                                   unsigned* __restrict__ genc, int n) {
    int lane = threadIdx.x & 63;
    int w = blockIdx.x * 4 + (threadIdx.x >> 6);
    int start = w * 64;
    if (start >= n) return;
    int end = start + 64; if (end > n) end = n;
    int cur = batch[start];
    float rm = -1e38f;
    for (int node = start; node < end; ++node) {
        int b = batch[node];                     // wave-uniform
        if (b != cur) {
            atomicMax(&genc[cur * 64 + lane], enc_f32(rm));
            cur = b;
            rm = -1e38f;
        }
        rm = fmaxf(rm, h[(size_t)node * 64 + lane]);
    }
    atomicMax(&genc[cur * 64 + lane], enc_f32(rm));
}

__global__ __launch_bounds__(64) void final_kernel(const unsigned* __restrict__ genc,
                                                   const float* __restrict__ linW,
                                                   const float* __restrict__ linb,
                                                   float* __restrict__ out) {
    int g = blockIdx.x;
    int lane = threadIdx.x;
    unsigned u = genc[g * 64 + lane];
    float v;
    if (u == 0u) {
        v = 0.0f;
    } else {
        unsigned b = (u & 0x80000000u) ? (u ^ 0x80000000u) : ~u;
        v = __uint_as_float(b);
    }
    float c0 = v * linW[lane * 2 + 0];
    float c1 = v * linW[lane * 2 + 1];
#pragma unroll
    for (int d = 32; d >= 1; d >>= 1) {
        c0 += __shfl_xor(c0, d, 64);
        c1 += __shfl_xor(c1, d, 64);
    }
    if (lane == 0) {
        out[g * 2 + 0] = c0 + linb[0];
        out[g * 2 + 1] = c1 + linb[1];
    }
}

// ---------------------------------------------------------------------------
// Launch
// ---------------------------------------------------------------------------
static inline size_t align_up(size_t v, size_t a) { return (v + a - 1) & ~(a - 1); }

extern "C" void kernel_launch(void* const* d_in, const int* in_sizes, int n_in,
                              void* d_out, int out_size, void* d_ws, size_t ws_size,
                              hipStream_t stream) {
    const float* x          = (const float*)d_in[0];
    const int*   edge_index = (const int*)d_in[1];
    const int*   batch      = (const int*)d_in[2];
    const float* W[5];
    const float* a_s[5];
    const float* a_d[5];
    const float* bias[5];
    for (int l = 0; l < 5; ++l) {
        W[l]    = (const float*)d_in[3 + 4 * l + 0];
        a_s[l]  = (const float*)d_in[3 + 4 * l + 1];
        a_d[l]  = (const float*)d_in[3 + 4 * l + 2];
        bias[l] = (const float*)d_in[3 + 4 * l + 3];
    }
    const float* linW = (const float*)d_in[23];
    const float* linb = (const float*)d_in[24];
    float* out = (float*)d_out;

    const int N = N_NODES;
    const int E = in_sizes[1] / 2;
    const int* srcp = edge_index;
    const int* dstp = edge_index + E;

    // workspace partition
    char* p = (char*)d_ws;
    int* bcount = (int*)p;        p += align_up((size_t)NBKT * 4, 256);
    int* bbase  = (int*)p;        p += align_up((size_t)(NBKT + 1) * 4, 256);
    int* bfill  = (int*)p;        p += align_up((size_t)NBKT * 4, 256);
    int* off    = (int*)p;        p += align_up((size_t)(N + 1) * 4, 256);
    int* esrc   = (int*)p;        p += align_up((size_t)E * 4, 256);
    float* lsb  = (float*)p;      p += align_up((size_t)N * 4, 256);
    float* ldb  = (float*)p;      p += align_up((size_t)N * 4, 256);
    float* h_a  = (float*)p;      p += align_up((size_t)N * 64 * 4, 256);
    float* h_b  = (float*)p;      p += align_up((size_t)N * 64 * 4, 256);
    unsigned* genc = (unsigned*)p; p += align_up((size_t)G_GRAPHS * 64 * 4, 256);

    // ebuck (E int2 = 12.8MB) aliases h_b (25.6MB): fully consumed by
    // bucket_csr before the first gemm writes h_b.
    int2* ebuck = (int2*)h_b;

    hipMemsetAsync(bcount, 0, (size_t)NBKT * 4, stream);
    hipMemsetAsync(genc, 0, (size_t)G_GRAPHS * 64 * 4, stream);

    int pb2 = (E + CHUNK_E - 1) / CHUNK_E;
    bucket_hist_kernel<<<pb2, 256, 0, stream>>>(dstp, bcount, E);
    bucket_scan_kernel<<<1, 256, 0, stream>>>(bcount, bbase, bfill, off, N);
    partition_kernel<<<pb2, 256, 0, stream>>>(srcp, dstp, bfill, ebuck, E);
    bucket_csr_kernel<<<NBKT, 256, 0, stream>>>(ebuck, bbase, off, esrc, N);

    int nb = (N + 15) / 16;   // 16 nodes per block (16-lane group per node)
    int gt = (N + 127) / 128; // GEMM: 128-node tiles, 512 threads
    gemm_tile_kernel<14, 16><<<gt, 512, 0, stream>>>(x, W[0], a_s[0], a_d[0],
                                                     h_b, lsb, ldb, N);
    gat_aggregate_kernel<<<nb, 256, 0, stream>>>(h_b, lsb, ldb, off, esrc,
                                                 bias[0], h_a, N);
    for (int l = 1; l < 5; ++l) {
        gemm_tile_kernel<64, 64><<<gt, 512, 0, stream>>>(h_a, W[l], a_s[l], a_d[l],
                                                         h_b, lsb, ldb, N);
        gat_aggregate_kernel<<<nb, 256, 0, stream>>>(h_b, lsb, ldb, off, esrc,
                                                     bias[l], h_a, N);
    }

    int pw = (N + 63) / 64;
    int pbk = (pw + 3) / 4;
    pool_kernel<<<pbk, 256, 0, stream>>>(h_a, batch, genc, N);
    final_kernel<<<G_GRAPHS, 64, 0, stream>>>(genc, linW, linb, out);
}

// Round 8
// 717.361 us; speedup vs baseline: 1.0011x; 1.0011x over previous
//
#include <hip/hip_runtime.h>
#include <math.h>

#define N_NODES 100000
#define H_DIM 64
#define G_GRAPHS 512
#define NEG_SLOPE 0.2f

// bucketed CSR-build params
#define BSHIFT 9                         // 512 nodes per bucket
#define NBKT ((N_NODES + (1 << BSHIFT) - 1) >> BSHIFT)   // 196
#define CHUNK_E 4096                     // edges per partition block (16/thread)

#define DEG_CAP 96                       // staged edges per node (multiple of 8; max obs deg ~45)

// ---------------------------------------------------------------------------
// CSR build, bucket-first: no per-edge global atomics anywhere.
// ---------------------------------------------------------------------------

// 196-bin LDS histogram -> 196 global atomics per block
__global__ __launch_bounds__(256) void bucket_hist_kernel(const int* __restrict__ dst,
                                                          int* __restrict__ bcount, int E) {
    __shared__ int lh[NBKT];
    int t = threadIdx.x;
    for (int i = t; i < NBKT; i += 256) lh[i] = 0;
    __syncthreads();
    int base = blockIdx.x * CHUNK_E;
#pragma unroll
    for (int k = 0; k < 16; ++k) {
        int e = base + k * 256 + t;
        if (e < E) atomicAdd(&lh[dst[e] >> BSHIFT], 1);
    }
    __syncthreads();
    for (int i = t; i < NBKT; i += 256) {
        int c = lh[i];
        if (c) atomicAdd(&bcount[i], c);
    }
}

// single block: exclusive scan of 196 bucket counts -> bbase[0..NBKT], bfill copy
__global__ __launch_bounds__(256) void bucket_scan_kernel(const int* __restrict__ bcount,
                                                          int* __restrict__ bbase,
                                                          int* __restrict__ bfill,
                                                          int* __restrict__ off, int n) {
    __shared__ int sm[256];
    int t = threadIdx.x;
    sm[t] = (t < NBKT) ? bcount[t] : 0;
    __syncthreads();
    for (int d = 1; d < 256; d <<= 1) {
        int v = (t >= d) ? sm[t - d] : 0;
        __syncthreads();
        sm[t] += v;
        __syncthreads();
    }
    if (t < NBKT) {
        int ex = (t == 0) ? 0 : sm[t - 1];
        bbase[t] = ex;
        bfill[t] = ex;
    }
    if (t == 0) {
        bbase[NBKT] = sm[255];       // = E
        off[n] = sm[255];
    }
}

// Radix-partition edges by dst bucket. LDS histogram -> one global atomicAdd
// per (block,bucket) -> LDS-rank -> writes are contiguous runs per bucket.
__global__ __launch_bounds__(256) void partition_kernel(const int* __restrict__ src,
                                                        const int* __restrict__ dst,
                                                        int* __restrict__ bfill,
                                                        int2* __restrict__ ebuck, int E) {
    __shared__ int lh[NBKT];
    __shared__ int lbase[NBKT];
    int t = threadIdx.x;
    int base = blockIdx.x * CHUNK_E;
    for (int i = t; i < NBKT; i += 256) lh[i] = 0;
    __syncthreads();

    int s[16], d[16], bk[16];
#pragma unroll
    for (int k = 0; k < 16; ++k) {
        int e = base + k * 256 + t;
        if (e < E) {
            s[k] = src[e];
            d[k] = dst[e];
            bk[k] = d[k] >> BSHIFT;
            atomicAdd(&lh[bk[k]], 1);
        } else {
            bk[k] = -1;
        }
    }
    __syncthreads();
    for (int i = t; i < NBKT; i += 256) {
        int c = lh[i];
        lbase[i] = c ? atomicAdd(&bfill[i], c) : 0;
        lh[i] = 0;
    }
    __syncthreads();
#pragma unroll
    for (int k = 0; k < 16; ++k) {
        if (bk[k] >= 0) {
            int r = atomicAdd(&lh[bk[k]], 1);
            ebuck[lbase[bk[k]] + r] = make_int2(s[k], d[k]);
        }
    }
}

// One block per bucket: LDS 512-bin node histogram -> LDS scan -> off[] write,
// then rank each edge via LDS atomicAdd and store esrc at its final CSR slot.
__global__ __launch_bounds__(256) void bucket_csr_kernel(const int2* __restrict__ ebuck,
                                                         const int* __restrict__ bbase,
                                                         int* __restrict__ off,
                                                         int* __restrict__ esrc, int n) {
    __shared__ int cnt[512];
    __shared__ int loff[512];
    __shared__ int sm[256];
    int b = blockIdx.x;
    int t = threadIdx.x;
    int ebeg = bbase[b];
    int eend = bbase[b + 1];
    int nbeg = b << BSHIFT;
    int nloc = n - nbeg; if (nloc > 512) nloc = 512;

    cnt[t] = 0; cnt[t + 256] = 0;
    __syncthreads();
    for (int e = ebeg + t; e < eend; e += 256) {
        atomicAdd(&cnt[ebuck[e].y - nbeg], 1);
    }
    __syncthreads();
    // exclusive scan of 512 counts (2 per thread)
    int c0 = cnt[2 * t], c1 = cnt[2 * t + 1];
    sm[t] = c0 + c1;
    __syncthreads();
    for (int d = 1; d < 256; d <<= 1) {
        int v = (t >= d) ? sm[t - d] : 0;
        __syncthreads();
        sm[t] += v;
        __syncthreads();
    }
    int basep = (t == 0) ? 0 : sm[t - 1];
    loff[2 * t] = basep;
    loff[2 * t + 1] = basep + c0;
    // reuse cnt as rank counters
    cnt[2 * t] = 0; cnt[2 * t + 1] = 0;
    __syncthreads();
    // write global off for this bucket's nodes
    for (int i = t; i < nloc; i += 256) off[nbeg + i] = ebeg + loff[i];
    // rank + final scatter (writes stay inside this bucket's esrc window)
    for (int e = ebeg + t; e < eend; e += 256) {
        int2 sd = ebuck[e];
        int d = sd.y - nbeg;
        int r = atomicAdd(&cnt[d], 1);
        esrc[ebeg + loff[d] + r] = sd.x;
    }
}

// ---------------------------------------------------------------------------
// Tiled GEMM + fused attention logits (v8 = proven v6 structure):
// 128-node tile; x-tile + zero-padded W staged in LDS (aligned, exactly-once
// HBM reads). 512 threads: (f4 = t&15, ng = t>>4 in [0,32)) computes
// 4 features x 4 rows (rows ng + 32*i) in registers, 32 VGPR, 3 blocks/CU.
// ---------------------------------------------------------------------------
template <int FIN, int FINP, int XSTR>
__global__ __launch_bounds__(512, 8) void gemm_tile_kernel(
        const float* __restrict__ act, const float* __restrict__ W,
        const float* __restrict__ a_s, const float* __restrict__ a_d,
        float* __restrict__ h, float* __restrict__ ls, float* __restrict__ ld,
        int n) {
    __shared__ float sx[128 * XSTR];
    __shared__ float sw[FINP * 64];
    int t = threadIdx.x;
    int tb = blockIdx.x * 128;
    int nrow = n - tb; if (nrow > 128) nrow = 128;

    // stage W, zero-padded for k in [FIN, FINP)
    {
        const float4* Wv = (const float4*)W;
        float4* swv = (float4*)sw;
        for (int i = t; i < FINP * 16; i += 512) {
            int k = i >> 4;
            swv[i] = (k < FIN) ? Wv[i] : make_float4(0.0f, 0.0f, 0.0f, 0.0f);
        }
    }
    // stage x tile
    if (FIN == 64) {
        for (int i = t; i < 128 * 16; i += 512) {
            int r = i >> 4, c4 = i & 15;
            float4 v = make_float4(0.0f, 0.0f, 0.0f, 0.0f);
            if (r < nrow) v = *(const float4*)(act + (size_t)(tb + r) * 64 + c4 * 4);
            *(float4*)(sx + r * XSTR + c4 * 4) = v;
        }
    } else {
        // scalar staging for unaligned 14-float rows; pad cols [FIN,FINP) to 0
        int c = t & 15;
        for (int r = t >> 4; r < 128; r += 32) {
            float v = 0.0f;
            if (r < nrow && c < FIN) v = act[(size_t)(tb + r) * FIN + c];
            sx[r * XSTR + c] = v;
        }
    }
    __syncthreads();

    int f4 = t & 15;
    int ng = t >> 4;          // [0, 32)

    float4 acc[4];
#pragma unroll
    for (int i = 0; i < 4; ++i) acc[i] = make_float4(0.0f, 0.0f, 0.0f, 0.0f);

    for (int k4 = 0; k4 < FINP; k4 += 4) {
        float4 w0 = *(const float4*)(sw + (k4 + 0) * 64 + f4 * 4);
        float4 w1 = *(const float4*)(sw + (k4 + 1) * 64 + f4 * 4);
        float4 w2 = *(const float4*)(sw + (k4 + 2) * 64 + f4 * 4);
        float4 w3 = *(const float4*)(sw + (k4 + 3) * 64 + f4 * 4);
#pragma unroll
        for (int i = 0; i < 4; ++i) {
            float4 xv = *(const float4*)(sx + (ng + 32 * i) * XSTR + k4);
            acc[i].x = fmaf(xv.x, w0.x, acc[i].x);
            acc[i].y = fmaf(xv.x, w0.y, acc[i].y);
            acc[i].z = fmaf(xv.x, w0.z, acc[i].z);
            acc[i].w = fmaf(xv.x, w0.w, acc[i].w);
            acc[i].x = fmaf(xv.y, w1.x, acc[i].x);
            acc[i].y = fmaf(xv.y, w1.y, acc[i].y);
            acc[i].z = fmaf(xv.y, w1.z, acc[i].z);
            acc[i].w = fmaf(xv.y, w1.w, acc[i].w);
            acc[i].x = fmaf(xv.z, w2.x, acc[i].x);
            acc[i].y = fmaf(xv.z, w2.y, acc[i].y);
            acc[i].z = fmaf(xv.z, w2.z, acc[i].z);
            acc[i].w = fmaf(xv.z, w2.w, acc[i].w);
            acc[i].x = fmaf(xv.w, w3.x, acc[i].x);
            acc[i].y = fmaf(xv.w, w3.y, acc[i].y);
            acc[i].z = fmaf(xv.w, w3.z, acc[i].z);
            acc[i].w = fmaf(xv.w, w3.w, acc[i].w);
        }
    }

    float4 as4 = *(const float4*)(a_s + f4 * 4);
    float4 ad4 = *(const float4*)(a_d + f4 * 4);
#pragma unroll
    for (int i = 0; i < 4; ++i) {
        int r = ng + 32 * i;
        if (r < nrow) {                       // uniform within the 16-lane group
            int node = tb + r;
            *(float4*)(h + (size_t)node * 64 + f4 * 4) = acc[i];
            float vs = acc[i].x * as4.x + acc[i].y * as4.y +
                       acc[i].z * as4.z + acc[i].w * as4.w;
            float vd = acc[i].x * ad4.x + acc[i].y * ad4.y +
                       acc[i].z * ad4.z + acc[i].w * ad4.w;
            vs += __shfl_xor(vs, 1, 64); vd += __shfl_xor(vd, 1, 64);
            vs += __shfl_xor(vs, 2, 64); vd += __shfl_xor(vd, 2, 64);
            vs += __shfl_xor(vs, 4, 64); vd += __shfl_xor(vd, 4, 64);
            vs += __shfl_xor(vs, 8, 64); vd += __shfl_xor(vd, 8, 64);
            if (f4 == 0) { ls[node] = vs; ld[node] = vd; }
        }
    }
}

// ---------------------------------------------------------------------------
// GAT aggregation (v7, kept: ~26us/dispatch): 16-lane group per node,
// LDS-staged (src,p), 8-wide single-stage gather, launch_bounds(256,8)
// pins VGPR <= 64 so occupancy stays at 8 blocks/CU.
// ---------------------------------------------------------------------------
__global__ __launch_bounds__(256, 8) void gat_aggregate_kernel(
        const float* __restrict__ h, const float* __restrict__ ls,
        const float* __restrict__ ld, const int* __restrict__ off,
        const int* __restrict__ esrc, const float* __restrict__ bias,
        float* __restrict__ hout, int n) {
    __shared__ int2 smq[16 * DEG_CAP];       // .x = src, .y = ls bits then p bits
    int t = threadIdx.x;
    int fl = t & 15;
    int g = t >> 4;
    int node = blockIdx.x * 16 + g;
    if (node >= n) return;
    int2* sq = smq + g * DEG_CAP;
    int fl4 = fl * 4;

    int jb = off[node];
    int je = off[node + 1];
    int deg = je - jb;
    int degc = (deg < DEG_CAP) ? deg : DEG_CAP;
    float ldv = ld[node];
    float lself = ls[node];

    // pass 1: gather ls, stage, running max of raw ls (leaky is monotone)
    float mm = lself;
    for (int c = fl; c < degc; c += 16) {
        int s = esrc[jb + c];
        float v = ls[s];
        sq[c] = make_int2(s, __float_as_int(v));
        mm = fmaxf(mm, v);
    }
    for (int c = degc + fl; c < deg; c += 16) {        // overflow: max only
        mm = fmaxf(mm, ls[esrc[jb + c]]);
    }
    mm = fmaxf(mm, __shfl_xor(mm, 8, 64));
    mm = fmaxf(mm, __shfl_xor(mm, 4, 64));
    mm = fmaxf(mm, __shfl_xor(mm, 2, 64));
    mm = fmaxf(mm, __shfl_xor(mm, 1, 64));
    float mraw = mm + ldv;
    float m = (mraw >= 0.0f) ? mraw : NEG_SLOPE * mraw;

    // pass 2: lsv -> p in LDS, lane-partial den
    float denl = 0.0f;
    for (int c = fl; c < degc; c += 16) {
        float e = __int_as_float(sq[c].y) + ldv;
        e = (e >= 0.0f) ? e : NEG_SLOPE * e;
        float p = __expf(e - m);
        sq[c].y = __float_as_int(p);
        denl += p;
    }
    // pad to multiple of 8 with (self, p=0): exact no-op, row is cache-hot
    int degc8 = (degc + 7) & ~7;
    if (fl < degc8 - degc) sq[degc + fl] = make_int2(node, 0);

    denl += __shfl_xor(denl, 8, 64);
    denl += __shfl_xor(denl, 4, 64);
    denl += __shfl_xor(denl, 2, 64);
    denl += __shfl_xor(denl, 1, 64);

    // gather loop: 8 independent 256B row loads in flight per group
    float4 acc = make_float4(0.0f, 0.0f, 0.0f, 0.0f);
    for (int c = 0; c < degc8; c += 8) {
        int2 e0 = sq[c + 0];
        int2 e1 = sq[c + 1];
        int2 e2 = sq[c + 2];
        int2 e3 = sq[c + 3];
        int2 e4 = sq[c + 4];
        int2 e5 = sq[c + 5];
        int2 e6 = sq[c + 6];
        int2 e7 = sq[c + 7];
        const float4 h0 = *(const float4*)(h + (size_t)e0.x * 64 + fl4);
        const float4 h1 = *(const float4*)(h + (size_t)e1.x * 64 + fl4);
        const float4 h2 = *(const float4*)(h + (size_t)e2.x * 64 + fl4);
        const float4 h3 = *(const float4*)(h + (size_t)e3.x * 64 + fl4);
        const float4 h4 = *(const float4*)(h + (size_t)e4.x * 64 + fl4);
        const float4 h5 = *(const float4*)(h + (size_t)e5.x * 64 + fl4);
        const float4 h6 = *(const float4*)(h + (size_t)e6.x * 64 + fl4);
        const float4 h7 = *(const float4*)(h + (size_t)e7.x * 64 + fl4);
        float p0 = __int_as_float(e0.y), p1 = __int_as_float(e1.y);
        float p2 = __int_as_float(e2.y), p3 = __int_as_float(e3.y);
        float p4 = __int_as_float(e4.y), p5 = __int_as_float(e5.y);
        float p6 = __int_as_float(e6.y), p7 = __int_as_float(e7.y);
        acc.x = fmaf(p0, h0.x, acc.x); acc.y = fmaf(p0, h0.y, acc.y);
        acc.z = fmaf(p0, h0.z, acc.z); acc.w = fmaf(p0, h0.w, acc.w);
        acc.x = fmaf(p1, h1.x, acc.x); acc.y = fmaf(p1, h1.y, acc.y);
        acc.z = fmaf(p1, h1.z, acc.z); acc.w = fmaf(p1, h1.w, acc.w);
        acc.x = fmaf(p2, h2.x, acc.x); acc.y = fmaf(p2, h2.y, acc.y);
        acc.z = fmaf(p2, h2.z, acc.z); acc.w = fmaf(p2, h2.w, acc.w);
        acc.x = fmaf(p3, h3.x, acc.x); acc.y = fmaf(p3, h3.y, acc.y);
        acc.z = fmaf(p3, h3.z, acc.z); acc.w = fmaf(p3, h3.w, acc.w);
        acc.x = fmaf(p4, h4.x, acc.x); acc.y = fmaf(p4, h4.y, acc.y);
        acc.z = fmaf(p4, h4.z, acc.z); acc.w = fmaf(p4, h4.w, acc.w);
        acc.x = fmaf(p5, h5.x, acc.x); acc.y = fmaf(p5, h5.y, acc.y);
        acc.z = fmaf(p5, h5.z, acc.z); acc.w = fmaf(p5, h5.w, acc.w);
        acc.x = fmaf(p6, h6.x, acc.x); acc.y = fmaf(p6, h6.y, acc.y);
        acc.z = fmaf(p6, h6.z, acc.z); acc.w = fmaf(p6, h6.w, acc.w);
        acc.x = fmaf(p7, h7.x, acc.x); acc.y = fmaf(p7, h7.y, acc.y);
        acc.z = fmaf(p7, h7.z, acc.z); acc.w = fmaf(p7, h7.w, acc.w);
    }

    // overflow tail (deg > DEG_CAP, ~never): serial, group-uniform den part
    float den_of = 0.0f;
    for (int j = jb + DEG_CAP; j < je; ++j) {
        int s = esrc[j];
        float e = ls[s] + ldv;
        e = (e >= 0.0f) ? e : NEG_SLOPE * e;
        float p = __expf(e - m);
        den_of += p;
        const float4 hv = *(const float4*)(h + (size_t)s * 64 + fl4);
        acc.x = fmaf(p, hv.x, acc.x);
        acc.y = fmaf(p, hv.y, acc.y);
        acc.z = fmaf(p, hv.z, acc.z);
        acc.w = fmaf(p, hv.w, acc.w);
    }

    // self loop
    const float4 hs = *(const float4*)(h + (size_t)node * 64 + fl4);
    float e0s = lself + ldv;
    e0s = (e0s >= 0.0f) ? e0s : NEG_SLOPE * e0s;
    float p0s = __expf(e0s - m);
    float den = denl + den_of + p0s;
    acc.x = fmaf(p0s, hs.x, acc.x);
    acc.y = fmaf(p0s, hs.y, acc.y);
    acc.z = fmaf(p0s, hs.z, acc.z);
    acc.w = fmaf(p0s, hs.w, acc.w);

    const float4 b4 = *(const float4*)(bias + fl4);
    float inv = 1.0f / den;
    float4 o;
    o.x = acc.x * inv + b4.x;
    o.y = acc.y * inv + b4.y;
    o.z = acc.z * inv + b4.z;
    o.w = acc.w * inv + b4.w;
    o.x = (o.x > 0.0f) ? o.x : expm1f(o.x);
    o.y = (o.y > 0.0f) ? o.y : expm1f(o.y);
    o.z = (o.z > 0.0f) ? o.z : expm1f(o.z);
    o.w = (o.w > 0.0f) ? o.w : expm1f(o.w);
    *(float4*)(hout + (size_t)node * 64 + fl4) = o;
}

// ---------------------------------------------------------------------------
// Global max pool: run-length (batch is sorted) + encoded atomicMax
// ---------------------------------------------------------------------------
__device__ __forceinline__ unsigned enc_f32(float f) {
    unsigned b = __float_as_uint(f);
    return (b & 0x80000000u) ? ~b : (b | 0x80000000u);
}

__global__ __launch_bounds__(256) void pool_kernel(const float* __restrict__ h,
                                                   const int* __restrict__ batch,
                                                   unsigned* __restrict__ genc, int n) {
    int lane = threadIdx.x & 63;
    int w = blockIdx.x * 4 + (threadIdx.x >> 6);
    int start = w * 64;
    if (start >= n) return;
    int end = start + 64; if (end > n) end = n;
    int cur = batch[start];
    float rm = -1e38f;
    for (int node = start; node < end; ++node) {
        int b = batch[node];                     // wave-uniform
        if (b != cur) {
            atomicMax(&genc[cur * 64 + lane], enc_f32(rm));
            cur = b;
            rm = -1e38f;
        }
        rm = fmaxf(rm, h[(size_t)node * 64 + lane]);
    }
    atomicMax(&genc[cur * 64 + lane], enc_f32(rm));
}

__global__ __launch_bounds__(64) void final_kernel(const unsigned* __restrict__ genc,
                                                   const float* __restrict__ linW,
                                                   const float* __restrict__ linb,
                                                   float* __restrict__ out) {
    int g = blockIdx.x;
    int lane = threadIdx.x;
    unsigned u = genc[g * 64 + lane];
    float v;
    if (u == 0u) {
        v = 0.0f;
    } else {
        unsigned b = (u & 0x80000000u) ? (u ^ 0x80000000u) : ~u;
        v = __uint_as_float(b);
    }
    float c0 = v * linW[lane * 2 + 0];
    float c1 = v * linW[lane * 2 + 1];
#pragma unroll
    for (int d = 32; d >= 1; d >>= 1) {
        c0 += __shfl_xor(c0, d, 64);
        c1 += __shfl_xor(c1, d, 64);
    }
    if (lane == 0) {
        out[g * 2 + 0] = c0 + linb[0];
        out[g * 2 + 1] = c1 + linb[1];
    }
}

// ---------------------------------------------------------------------------
// Launch
// ---------------------------------------------------------------------------
static inline size_t align_up(size_t v, size_t a) { return (v + a - 1) & ~(a - 1); }

extern "C" void kernel_launch(void* const* d_in, const int* in_sizes, int n_in,
                              void* d_out, int out_size, void* d_ws, size_t ws_size,
                              hipStream_t stream) {
    const float* x          = (const float*)d_in[0];
    const int*   edge_index = (const int*)d_in[1];
    const int*   batch      = (const int*)d_in[2];
    const float* W[5];
    const float* a_s[5];
    const float* a_d[5];
    const float* bias[5];
    for (int l = 0; l < 5; ++l) {
        W[l]    = (const float*)d_in[3 + 4 * l + 0];
        a_s[l]  = (const float*)d_in[3 + 4 * l + 1];
        a_d[l]  = (const float*)d_in[3 + 4 * l + 2];
        bias[l] = (const float*)d_in[3 + 4 * l + 3];
    }
    const float* linW = (const float*)d_in[23];
    const float* linb = (const float*)d_in[24];
    float* out = (float*)d_out;

    const int N = N_NODES;
    const int E = in_sizes[1] / 2;
    const int* srcp = edge_index;
    const int* dstp = edge_index + E;

    // workspace partition
    char* p = (char*)d_ws;
    int* bcount = (int*)p;        p += align_up((size_t)NBKT * 4, 256);
    int* bbase  = (int*)p;        p += align_up((size_t)(NBKT + 1) * 4, 256);
    int* bfill  = (int*)p;        p += align_up((size_t)NBKT * 4, 256);
    int* off    = (int*)p;        p += align_up((size_t)(N + 1) * 4, 256);
    int* esrc   = (int*)p;        p += align_up((size_t)E * 4, 256);
    float* lsb  = (float*)p;      p += align_up((size_t)N * 4, 256);
    float* ldb  = (float*)p;      p += align_up((size_t)N * 4, 256);
    float* h_a  = (float*)p;      p += align_up((size_t)N * 64 * 4, 256);
    float* h_b  = (float*)p;      p += align_up((size_t)N * 64 * 4, 256);
    unsigned* genc = (unsigned*)p; p += align_up((size_t)G_GRAPHS * 64 * 4, 256);

    // ebuck (E int2 = 12.8MB) aliases h_b (25.6MB): fully consumed by
    // bucket_csr before the first gemm writes h_b.
    int2* ebuck = (int2*)h_b;

    hipMemsetAsync(bcount, 0, (size_t)NBKT * 4, stream);
    hipMemsetAsync(genc, 0, (size_t)G_GRAPHS * 64 * 4, stream);

    int pb2 = (E + CHUNK_E - 1) / CHUNK_E;
    bucket_hist_kernel<<<pb2, 256, 0, stream>>>(dstp, bcount, E);
    bucket_scan_kernel<<<1, 256, 0, stream>>>(bcount, bbase, bfill, off, N);
    partition_kernel<<<pb2, 256, 0, stream>>>(srcp, dstp, bfill, ebuck, E);
    bucket_csr_kernel<<<NBKT, 256, 0, stream>>>(ebuck, bbase, off, esrc, N);

    int nb = (N + 15) / 16;   // 16 nodes per block (16-lane group per node)
    int gt = (N + 127) / 128; // GEMM: 128-node tiles, 512 threads
    gemm_tile_kernel<14, 16, 20><<<gt, 512, 0, stream>>>(x, W[0], a_s[0], a_d[0],
                                                         h_b, lsb, ldb, N);
    gat_aggregate_kernel<<<nb, 256, 0, stream>>>(h_b, lsb, ldb, off, esrc,
                                                 bias[0], h_a, N);
    for (int l = 1; l < 5; ++l) {
        gemm_tile_kernel<64, 64, 68><<<gt, 512, 0, stream>>>(h_a, W[l], a_s[l], a_d[l],
                                                             h_b, lsb, ldb, N);
        gat_aggregate_kernel<<<nb, 256, 0, stream>>>(h_b, lsb, ldb, off, esrc,
                                                     bias[l], h_a, N);
    }

    int pw = (N + 63) / 64;
    int pbk = (pw + 3) / 4;
    pool_kernel<<<pbk, 256, 0, stream>>>(h_a, batch, genc, N);
    final_kernel<<<G_GRAPHS, 64, 0, stream>>>(genc, linW, linb, out);
}

// Round 9
// 641.735 us; speedup vs baseline: 1.1191x; 1.1178x over previous
//
#include <hip/hip_runtime.h>
#include <math.h>

#define N_NODES 100000
#define H_DIM 64
#define G_GRAPHS 512
#define NEG_SLOPE 0.2f

// bucketed CSR-build params
#define BSHIFT 9                         // 512 nodes per bucket
#define NBKT ((N_NODES + (1 << BSHIFT) - 1) >> BSHIFT)   // 196
#define CHUNK_E 4096                     // edges per partition block (16/thread)

#define DEG_CAP 96                       // staged edges per node (multiple of 8; max obs deg ~45)

// ---------------------------------------------------------------------------
// CSR build, bucket-first: no per-edge global atomics anywhere.
// ---------------------------------------------------------------------------

// 196-bin LDS histogram -> 196 global atomics per block
__global__ __launch_bounds__(256) void bucket_hist_kernel(const int* __restrict__ dst,
                                                          int* __restrict__ bcount, int E) {
    __shared__ int lh[NBKT];
    int t = threadIdx.x;
    for (int i = t; i < NBKT; i += 256) lh[i] = 0;
    __syncthreads();
    int base = blockIdx.x * CHUNK_E;
#pragma unroll
    for (int k = 0; k < 16; ++k) {
        int e = base + k * 256 + t;
        if (e < E) atomicAdd(&lh[dst[e] >> BSHIFT], 1);
    }
    __syncthreads();
    for (int i = t; i < NBKT; i += 256) {
        int c = lh[i];
        if (c) atomicAdd(&bcount[i], c);
    }
}

// single block: exclusive scan of 196 bucket counts -> bbase[0..NBKT], bfill copy
__global__ __launch_bounds__(256) void bucket_scan_kernel(const int* __restrict__ bcount,
                                                          int* __restrict__ bbase,
                                                          int* __restrict__ bfill,
                                                          int* __restrict__ off, int n) {
    __shared__ int sm[256];
    int t = threadIdx.x;
    sm[t] = (t < NBKT) ? bcount[t] : 0;
    __syncthreads();
    for (int d = 1; d < 256; d <<= 1) {
        int v = (t >= d) ? sm[t - d] : 0;
        __syncthreads();
        sm[t] += v;
        __syncthreads();
    }
    if (t < NBKT) {
        int ex = (t == 0) ? 0 : sm[t - 1];
        bbase[t] = ex;
        bfill[t] = ex;
    }
    if (t == 0) {
        bbase[NBKT] = sm[255];       // = E
        off[n] = sm[255];
    }
}

// Radix-partition edges by dst bucket. LDS histogram -> one global atomicAdd
// per (block,bucket) -> LDS-rank -> writes are contiguous runs per bucket.
__global__ __launch_bounds__(256) void partition_kernel(const int* __restrict__ src,
                                                        const int* __restrict__ dst,
                                                        int* __restrict__ bfill,
                                                        int2* __restrict__ ebuck, int E) {
    __shared__ int lh[NBKT];
    __shared__ int lbase[NBKT];
    int t = threadIdx.x;
    int base = blockIdx.x * CHUNK_E;
    for (int i = t; i < NBKT; i += 256) lh[i] = 0;
    __syncthreads();

    int s[16], d[16], bk[16];
#pragma unroll
    for (int k = 0; k < 16; ++k) {
        int e = base + k * 256 + t;
        if (e < E) {
            s[k] = src[e];
            d[k] = dst[e];
            bk[k] = d[k] >> BSHIFT;
            atomicAdd(&lh[bk[k]], 1);
        } else {
            bk[k] = -1;
        }
    }
    __syncthreads();
    for (int i = t; i < NBKT; i += 256) {
        int c = lh[i];
        lbase[i] = c ? atomicAdd(&bfill[i], c) : 0;
        lh[i] = 0;
    }
    __syncthreads();
#pragma unroll
    for (int k = 0; k < 16; ++k) {
        if (bk[k] >= 0) {
            int r = atomicAdd(&lh[bk[k]], 1);
            ebuck[lbase[bk[k]] + r] = make_int2(s[k], d[k]);
        }
    }
}

// One block per bucket: LDS 512-bin node histogram -> LDS scan -> off[] write,
// then rank each edge via LDS atomicAdd and store esrc at its final CSR slot.
__global__ __launch_bounds__(256) void bucket_csr_kernel(const int2* __restrict__ ebuck,
                                                         const int* __restrict__ bbase,
                                                         int* __restrict__ off,
                                                         int* __restrict__ esrc, int n) {
    __shared__ int cnt[512];
    __shared__ int loff[512];
    __shared__ int sm[256];
    int b = blockIdx.x;
    int t = threadIdx.x;
    int ebeg = bbase[b];
    int eend = bbase[b + 1];
    int nbeg = b << BSHIFT;
    int nloc = n - nbeg; if (nloc > 512) nloc = 512;

    cnt[t] = 0; cnt[t + 256] = 0;
    __syncthreads();
    for (int e = ebeg + t; e < eend; e += 256) {
        atomicAdd(&cnt[ebuck[e].y - nbeg], 1);
    }
    __syncthreads();
    // exclusive scan of 512 counts (2 per thread)
    int c0 = cnt[2 * t], c1 = cnt[2 * t + 1];
    sm[t] = c0 + c1;
    __syncthreads();
    for (int d = 1; d < 256; d <<= 1) {
        int v = (t >= d) ? sm[t - d] : 0;
        __syncthreads();
        sm[t] += v;
        __syncthreads();
    }
    int basep = (t == 0) ? 0 : sm[t - 1];
    loff[2 * t] = basep;
    loff[2 * t + 1] = basep + c0;
    // reuse cnt as rank counters
    cnt[2 * t] = 0; cnt[2 * t + 1] = 0;
    __syncthreads();
    // write global off for this bucket's nodes
    for (int i = t; i < nloc; i += 256) off[nbeg + i] = ebeg + loff[i];
    // rank + final scatter (writes stay inside this bucket's esrc window)
    for (int e = ebeg + t; e < eend; e += 256) {
        int2 sd = ebuck[e];
        int d = sd.y - nbeg;
        int r = atomicAdd(&cnt[d], 1);
        esrc[ebeg + loff[d] + r] = sd.x;
    }
}

// ---------------------------------------------------------------------------
// Tiled GEMM + fused attention logits (v9 = exact round-4/5 structure, the
// only gemm config measured fast end-to-end): 256 threads, 128-node tile,
// x-tile + zero-padded W staged in LDS, thread (f4 = t&15, ng = t>>4 in
// [0,16)) computes 4 features x 8 rows (rows ng + 16*i) in registers.
// Plain __launch_bounds__(256) -- no min-waves constraint.
// ---------------------------------------------------------------------------
template <int FIN, int FINP, int XSTR>
__global__ __launch_bounds__(256) void gemm_tile_kernel(
        const float* __restrict__ act, const float* __restrict__ W,
        const float* __restrict__ a_s, const float* __restrict__ a_d,
        float* __restrict__ h, float* __restrict__ ls, float* __restrict__ ld,
        int n) {
    __shared__ float sx[128 * XSTR];
    __shared__ float sw[FINP * 64];
    int t = threadIdx.x;
    int tb = blockIdx.x * 128;
    int nrow = n - tb; if (nrow > 128) nrow = 128;

    // stage W, zero-padded for k in [FIN, FINP)
    {
        const float4* Wv = (const float4*)W;
        float4* swv = (float4*)sw;
        for (int i = t; i < FINP * 16; i += 256) {
            int k = i >> 4;
            swv[i] = (k < FIN) ? Wv[i] : make_float4(0.0f, 0.0f, 0.0f, 0.0f);
        }
    }
    // stage x tile
    if (FIN == 64) {
        for (int i = t; i < 128 * 16; i += 256) {
            int r = i >> 4, c4 = i & 15;
            float4 v = make_float4(0.0f, 0.0f, 0.0f, 0.0f);
            if (r < nrow) v = *(const float4*)(act + (size_t)(tb + r) * 64 + c4 * 4);
            *(float4*)(sx + r * XSTR + c4 * 4) = v;
        }
    } else {
        // scalar staging for unaligned 14-float rows; pad cols [FIN,FINP) to 0
        int c = t & 15;
        for (int r = t >> 4; r < 128; r += 16) {
            float v = 0.0f;
            if (r < nrow && c < FIN) v = act[(size_t)(tb + r) * FIN + c];
            sx[r * XSTR + c] = v;
        }
    }
    __syncthreads();

    int f4 = t & 15;
    int ng = t >> 4;          // [0, 16)

    float4 acc[8];
#pragma unroll
    for (int i = 0; i < 8; ++i) acc[i] = make_float4(0.0f, 0.0f, 0.0f, 0.0f);

    for (int k4 = 0; k4 < FINP; k4 += 4) {
        float4 w0 = *(const float4*)(sw + (k4 + 0) * 64 + f4 * 4);
        float4 w1 = *(const float4*)(sw + (k4 + 1) * 64 + f4 * 4);
        float4 w2 = *(const float4*)(sw + (k4 + 2) * 64 + f4 * 4);
        float4 w3 = *(const float4*)(sw + (k4 + 3) * 64 + f4 * 4);
#pragma unroll
        for (int i = 0; i < 8; ++i) {
            float4 xv = *(const float4*)(sx + (ng + 16 * i) * XSTR + k4);
            acc[i].x = fmaf(xv.x, w0.x, acc[i].x);
            acc[i].y = fmaf(xv.x, w0.y, acc[i].y);
            acc[i].z = fmaf(xv.x, w0.z, acc[i].z);
            acc[i].w = fmaf(xv.x, w0.w, acc[i].w);
            acc[i].x = fmaf(xv.y, w1.x, acc[i].x);
            acc[i].y = fmaf(xv.y, w1.y, acc[i].y);
            acc[i].z = fmaf(xv.y, w1.z, acc[i].z);
            acc[i].w = fmaf(xv.y, w1.w, acc[i].w);
            acc[i].x = fmaf(xv.z, w2.x, acc[i].x);
            acc[i].y = fmaf(xv.z, w2.y, acc[i].y);
            acc[i].z = fmaf(xv.z, w2.z, acc[i].z);
            acc[i].w = fmaf(xv.z, w2.w, acc[i].w);
            acc[i].x = fmaf(xv.w, w3.x, acc[i].x);
            acc[i].y = fmaf(xv.w, w3.y, acc[i].y);
            acc[i].z = fmaf(xv.w, w3.z, acc[i].z);
            acc[i].w = fmaf(xv.w, w3.w, acc[i].w);
        }
    }

    float4 as4 = *(const float4*)(a_s + f4 * 4);
    float4 ad4 = *(const float4*)(a_d + f4 * 4);
#pragma unroll
    for (int i = 0; i < 8; ++i) {
        int r = ng + 16 * i;
        if (r < nrow) {                       // uniform within the 16-lane group
            int node = tb + r;
            *(float4*)(h + (size_t)node * 64 + f4 * 4) = acc[i];
            float vs = acc[i].x * as4.x + acc[i].y * as4.y +
                       acc[i].z * as4.z + acc[i].w * as4.w;
            float vd = acc[i].x * ad4.x + acc[i].y * ad4.y +
                       acc[i].z * ad4.z + acc[i].w * ad4.w;
            vs += __shfl_xor(vs, 1, 64); vd += __shfl_xor(vd, 1, 64);
            vs += __shfl_xor(vs, 2, 64); vd += __shfl_xor(vd, 2, 64);
            vs += __shfl_xor(vs, 4, 64); vd += __shfl_xor(vd, 4, 64);
            vs += __shfl_xor(vs, 8, 64); vd += __shfl_xor(vd, 8, 64);
            if (f4 == 0) { ls[node] = vs; ld[node] = vd; }
        }
    }
}

// ---------------------------------------------------------------------------
// GAT aggregation (v8, kept): 16-lane group per node, LDS-staged (src,p),
// 8-wide single-stage gather, launch_bounds(256,8) pins VGPR <= 64 so
// occupancy stays at 8 blocks/CU.
// ---------------------------------------------------------------------------
__global__ __launch_bounds__(256, 8) void gat_aggregate_kernel(
        const float* __restrict__ h, const float* __restrict__ ls,
        const float* __restrict__ ld, const int* __restrict__ off,
        const int* __restrict__ esrc, const float* __restrict__ bias,
        float* __restrict__ hout, int n) {
    __shared__ int2 smq[16 * DEG_CAP];       // .x = src, .y = ls bits then p bits
    int t = threadIdx.x;
    int fl = t & 15;
    int g = t >> 4;
    int node = blockIdx.x * 16 + g;
    if (node >= n) return;
    int2* sq = smq + g * DEG_CAP;
    int fl4 = fl * 4;

    int jb = off[node];
    int je = off[node + 1];
    int deg = je - jb;
    int degc = (deg < DEG_CAP) ? deg : DEG_CAP;
    float ldv = ld[node];
    float lself = ls[node];

    // pass 1: gather ls, stage, running max of raw ls (leaky is monotone)
    float mm = lself;
    for (int c = fl; c < degc; c += 16) {
        int s = esrc[jb + c];
        float v = ls[s];
        sq[c] = make_int2(s, __float_as_int(v));
        mm = fmaxf(mm, v);
    }
    for (int c = degc + fl; c < deg; c += 16) {        // overflow: max only
        mm = fmaxf(mm, ls[esrc[jb + c]]);
    }
    mm = fmaxf(mm, __shfl_xor(mm, 8, 64));
    mm = fmaxf(mm, __shfl_xor(mm, 4, 64));
    mm = fmaxf(mm, __shfl_xor(mm, 2, 64));
    mm = fmaxf(mm, __shfl_xor(mm, 1, 64));
    float mraw = mm + ldv;
    float m = (mraw >= 0.0f) ? mraw : NEG_SLOPE * mraw;

    // pass 2: lsv -> p in LDS, lane-partial den
    float denl = 0.0f;
    for (int c = fl; c < degc; c += 16) {
        float e = __int_as_float(sq[c].y) + ldv;
        e = (e >= 0.0f) ? e : NEG_SLOPE * e;
        float p = __expf(e - m);
        sq[c].y = __float_as_int(p);
        denl += p;
    }
    // pad to multiple of 8 with (self, p=0): exact no-op, row is cache-hot
    int degc8 = (degc + 7) & ~7;
    if (fl < degc8 - degc) sq[degc + fl] = make_int2(node, 0);

    denl += __shfl_xor(denl, 8, 64);
    denl += __shfl_xor(denl, 4, 64);
    denl += __shfl_xor(denl, 2, 64);
    denl += __shfl_xor(denl, 1, 64);

    // gather loop: 8 independent 256B row loads in flight per group
    float4 acc = make_float4(0.0f, 0.0f, 0.0f, 0.0f);
    for (int c = 0; c < degc8; c += 8) {
        int2 e0 = sq[c + 0];
        int2 e1 = sq[c + 1];
        int2 e2 = sq[c + 2];
        int2 e3 = sq[c + 3];
        int2 e4 = sq[c + 4];
        int2 e5 = sq[c + 5];
        int2 e6 = sq[c + 6];
        int2 e7 = sq[c + 7];
        const float4 h0 = *(const float4*)(h + (size_t)e0.x * 64 + fl4);
        const float4 h1 = *(const float4*)(h + (size_t)e1.x * 64 + fl4);
        const float4 h2 = *(const float4*)(h + (size_t)e2.x * 64 + fl4);
        const float4 h3 = *(const float4*)(h + (size_t)e3.x * 64 + fl4);
        const float4 h4 = *(const float4*)(h + (size_t)e4.x * 64 + fl4);
        const float4 h5 = *(const float4*)(h + (size_t)e5.x * 64 + fl4);
        const float4 h6 = *(const float4*)(h + (size_t)e6.x * 64 + fl4);
        const float4 h7 = *(const float4*)(h + (size_t)e7.x * 64 + fl4);
        float p0 = __int_as_float(e0.y), p1 = __int_as_float(e1.y);
        float p2 = __int_as_float(e2.y), p3 = __int_as_float(e3.y);
        float p4 = __int_as_float(e4.y), p5 = __int_as_float(e5.y);
        float p6 = __int_as_float(e6.y), p7 = __int_as_float(e7.y);
        acc.x = fmaf(p0, h0.x, acc.x); acc.y = fmaf(p0, h0.y, acc.y);
        acc.z = fmaf(p0, h0.z, acc.z); acc.w = fmaf(p0, h0.w, acc.w);
        acc.x = fmaf(p1, h1.x, acc.x); acc.y = fmaf(p1, h1.y, acc.y);
        acc.z = fmaf(p1, h1.z, acc.z); acc.w = fmaf(p1, h1.w, acc.w);
        acc.x = fmaf(p2, h2.x, acc.x); acc.y = fmaf(p2, h2.y, acc.y);
        acc.z = fmaf(p2, h2.z, acc.z); acc.w = fmaf(p2, h2.w, acc.w);
        acc.x = fmaf(p3, h3.x, acc.x); acc.y = fmaf(p3, h3.y, acc.y);
        acc.z = fmaf(p3, h3.z, acc.z); acc.w = fmaf(p3, h3.w, acc.w);
        acc.x = fmaf(p4, h4.x, acc.x); acc.y = fmaf(p4, h4.y, acc.y);
        acc.z = fmaf(p4, h4.z, acc.z); acc.w = fmaf(p4, h4.w, acc.w);
        acc.x = fmaf(p5, h5.x, acc.x); acc.y = fmaf(p5, h5.y, acc.y);
        acc.z = fmaf(p5, h5.z, acc.z); acc.w = fmaf(p5, h5.w, acc.w);
        acc.x = fmaf(p6, h6.x, acc.x); acc.y = fmaf(p6, h6.y, acc.y);
        acc.z = fmaf(p6, h6.z, acc.z); acc.w = fmaf(p6, h6.w, acc.w);
        acc.x = fmaf(p7, h7.x, acc.x); acc.y = fmaf(p7, h7.y, acc.y);
        acc.z = fmaf(p7, h7.z, acc.z); acc.w = fmaf(p7, h7.w, acc.w);
    }

    // overflow tail (deg > DEG_CAP, ~never): serial, group-uniform den part
    float den_of = 0.0f;
    for (int j = jb + DEG_CAP; j < je; ++j) {
        int s = esrc[j];
        float e = ls[s] + ldv;
        e = (e >= 0.0f) ? e : NEG_SLOPE * e;
        float p = __expf(e - m);
        den_of += p;
        const float4 hv = *(const float4*)(h + (size_t)s * 64 + fl4);
        acc.x = fmaf(p, hv.x, acc.x);
        acc.y = fmaf(p, hv.y, acc.y);
        acc.z = fmaf(p, hv.z, acc.z);
        acc.w = fmaf(p, hv.w, acc.w);
    }

    // self loop
    const float4 hs = *(const float4*)(h + (size_t)node * 64 + fl4);
    float e0s = lself + ldv;
    e0s = (e0s >= 0.0f) ? e0s : NEG_SLOPE * e0s;
    float p0s = __expf(e0s - m);
    float den = denl + den_of + p0s;
    acc.x = fmaf(p0s, hs.x, acc.x);
    acc.y = fmaf(p0s, hs.y, acc.y);
    acc.z = fmaf(p0s, hs.z, acc.z);
    acc.w = fmaf(p0s, hs.w, acc.w);

    const float4 b4 = *(const float4*)(bias + fl4);
    float inv = 1.0f / den;
    float4 o;
    o.x = acc.x * inv + b4.x;
    o.y = acc.y * inv + b4.y;
    o.z = acc.z * inv + b4.z;
    o.w = acc.w * inv + b4.w;
    o.x = (o.x > 0.0f) ? o.x : expm1f(o.x);
    o.y = (o.y > 0.0f) ? o.y : expm1f(o.y);
    o.z = (o.z > 0.0f) ? o.z : expm1f(o.z);
    o.w = (o.w > 0.0f) ? o.w : expm1f(o.w);
    *(float4*)(hout + (size_t)node * 64 + fl4) = o;
}

// ---------------------------------------------------------------------------
// Global max pool: run-length (batch is sorted) + encoded atomicMax
// ---------------------------------------------------------------------------
__device__ __forceinline__ unsigned enc_f32(float f) {
    unsigned b = __float_as_uint(f);
    return (b & 0x80000000u) ? ~b : (b | 0x80000000u);
}

__global__ __launch_bounds__(256) void pool_kernel(const float* __restrict__ h,
                                                   const int* __restrict__ batch,
                                                   unsigned* __restrict__ genc, int n) {
    int lane = threadIdx.x & 63;
    int w = blockIdx.x * 4 + (threadIdx.x >> 6);
    int start = w * 64;
    if (start >= n) return;
    int end = start + 64; if (end > n) end = n;
    int cur = batch[start];
    float rm = -1e38f;
    for (int node = start; node < end; ++node) {
        int b = batch[node];                     // wave-uniform
        if (b != cur) {
            atomicMax(&genc[cur * 64 + lane], enc_f32(rm));
            cur = b;
            rm = -1e38f;
        }
        rm = fmaxf(rm, h[(size_t)node * 64 + lane]);
    }
    atomicMax(&genc[cur * 64 + lane], enc_f32(rm));
}

__global__ __launch_bounds__(64) void final_kernel(const unsigned* __restrict__ genc,
                                                   const float* __restrict__ linW,
                                                   const float* __restrict__ linb,
                                                   float* __restrict__ out) {
    int g = blockIdx.x;
    int lane = threadIdx.x;
    unsigned u = genc[g * 64 + lane];
    float v;
    if (u == 0u) {
        v = 0.0f;
    } else {
        unsigned b = (u & 0x80000000u) ? (u ^ 0x80000000u) : ~u;
        v = __uint_as_float(b);
    }
    float c0 = v * linW[lane * 2 + 0];
    float c1 = v * linW[lane * 2 + 1];
#pragma unroll
    for (int d = 32; d >= 1; d >>= 1) {
        c0 += __shfl_xor(c0, d, 64);
        c1 += __shfl_xor(c1, d, 64);
    }
    if (lane == 0) {
        out[g * 2 + 0] = c0 + linb[0];
        out[g * 2 + 1] = c1 + linb[1];
    }
}

// ---------------------------------------------------------------------------
// Launch
// ---------------------------------------------------------------------------
static inline size_t align_up(size_t v, size_t a) { return (v + a - 1) & ~(a - 1); }

extern "C" void kernel_launch(void* const* d_in, const int* in_sizes, int n_in,
                              void* d_out, int out_size, void* d_ws, size_t ws_size,
                              hipStream_t stream) {
    const float* x          = (const float*)d_in[0];
    const int*   edge_index = (const int*)d_in[1];
    const int*   batch      = (const int*)d_in[2];
    const float* W[5];
    const float* a_s[5];
    const float* a_d[5];
    const float* bias[5];
    for (int l = 0; l < 5; ++l) {
        W[l]    = (const float*)d_in[3 + 4 * l + 0];
        a_s[l]  = (const float*)d_in[3 + 4 * l + 1];
        a_d[l]  = (const float*)d_in[3 + 4 * l + 2];
        bias[l] = (const float*)d_in[3 + 4 * l + 3];
    }
    const float* linW = (const float*)d_in[23];
    const float* linb = (const float*)d_in[24];
    float* out = (float*)d_out;

    const int N = N_NODES;
    const int E = in_sizes[1] / 2;
    const int* srcp = edge_index;
    const int* dstp = edge_index + E;

    // workspace partition
    char* p = (char*)d_ws;
    int* bcount = (int*)p;        p += align_up((size_t)NBKT * 4, 256);
    int* bbase  = (int*)p;        p += align_up((size_t)(NBKT + 1) * 4, 256);
    int* bfill  = (int*)p;        p += align_up((size_t)NBKT * 4, 256);
    int* off    = (int*)p;        p += align_up((size_t)(N + 1) * 4, 256);
    int* esrc   = (int*)p;        p += align_up((size_t)E * 4, 256);
    float* lsb  = (float*)p;      p += align_up((size_t)N * 4, 256);
    float* ldb  = (float*)p;      p += align_up((size_t)N * 4, 256);
    float* h_a  = (float*)p;      p += align_up((size_t)N * 64 * 4, 256);
    float* h_b  = (float*)p;      p += align_up((size_t)N * 64 * 4, 256);
    unsigned* genc = (unsigned*)p; p += align_up((size_t)G_GRAPHS * 64 * 4, 256);

    // ebuck (E int2 = 12.8MB) aliases h_b (25.6MB): fully consumed by
    // bucket_csr before the first gemm writes h_b.
    int2* ebuck = (int2*)h_b;

    hipMemsetAsync(bcount, 0, (size_t)NBKT * 4, stream);
    hipMemsetAsync(genc, 0, (size_t)G_GRAPHS * 64 * 4, stream);

    int pb2 = (E + CHUNK_E - 1) / CHUNK_E;
    bucket_hist_kernel<<<pb2, 256, 0, stream>>>(dstp, bcount, E);
    bucket_scan_kernel<<<1, 256, 0, stream>>>(bcount, bbase, bfill, off, N);
    partition_kernel<<<pb2, 256, 0, stream>>>(srcp, dstp, bfill, ebuck, E);
    bucket_csr_kernel<<<NBKT, 256, 0, stream>>>(ebuck, bbase, off, esrc, N);

    int nb = (N + 15) / 16;   // 16 nodes per block (16-lane group per node)
    int gt = (N + 127) / 128; // GEMM: 128-node tiles, 256 threads (r5 config)
    gemm_tile_kernel<14, 16, 20><<<gt, 256, 0, stream>>>(x, W[0], a_s[0], a_d[0],
                                                         h_b, lsb, ldb, N);
    gat_aggregate_kernel<<<nb, 256, 0, stream>>>(h_b, lsb, ldb, off, esrc,
                                                 bias[0], h_a, N);
    for (int l = 1; l < 5; ++l) {
        gemm_tile_kernel<64, 64, 68><<<gt, 256, 0, stream>>>(h_a, W[l], a_s[l], a_d[l],
                                                             h_b, lsb, ldb, N);
        gat_aggregate_kernel<<<nb, 256, 0, stream>>>(h_b, lsb, ldb, off, esrc,
                                                     bias[l], h_a, N);
    }

    int pw = (N + 63) / 64;
    int pbk = (pw + 3) / 4;
    pool_kernel<<<pbk, 256, 0, stream>>>(h_a, batch, genc, N);
    final_kernel<<<G_GRAPHS, 64, 0, stream>>>(genc, linW, linb, out);
}

// Round 10
// 514.995 us; speedup vs baseline: 1.3945x; 1.2461x over previous
//
#include <hip/hip_runtime.h>
#include <hip/hip_fp16.h>
#include <math.h>

#define N_NODES 100000
#define H_DIM 64
#define G_GRAPHS 512
#define NEG_SLOPE 0.2f

// bucketed CSR-build params
#define BSHIFT 9                         // 512 nodes per bucket
#define NBKT ((N_NODES + (1 << BSHIFT) - 1) >> BSHIFT)   // 196
#define CHUNK_E 4096                     // edges per partition block (16/thread)

#define DEG_CAP 128                      // staged edges per node (Poisson(16) max ~45)

// ---------------------------------------------------------------------------
// CSR build, bucket-first: no per-edge global atomics anywhere.
// ---------------------------------------------------------------------------

// 196-bin LDS histogram -> 196 global atomics per block
__global__ __launch_bounds__(256) void bucket_hist_kernel(const int* __restrict__ dst,
                                                          int* __restrict__ bcount, int E) {
    __shared__ int lh[NBKT];
    int t = threadIdx.x;
    for (int i = t; i < NBKT; i += 256) lh[i] = 0;
    __syncthreads();
    int base = blockIdx.x * CHUNK_E;
#pragma unroll
    for (int k = 0; k < 16; ++k) {
        int e = base + k * 256 + t;
        if (e < E) atomicAdd(&lh[dst[e] >> BSHIFT], 1);
    }
    __syncthreads();
    for (int i = t; i < NBKT; i += 256) {
        int c = lh[i];
        if (c) atomicAdd(&bcount[i], c);
    }
}

// single block: exclusive scan of 196 bucket counts -> bbase[0..NBKT], bfill copy
__global__ __launch_bounds__(256) void bucket_scan_kernel(const int* __restrict__ bcount,
                                                          int* __restrict__ bbase,
                                                          int* __restrict__ bfill,
                                                          int* __restrict__ off, int n) {
    __shared__ int sm[256];
    int t = threadIdx.x;
    sm[t] = (t < NBKT) ? bcount[t] : 0;
    __syncthreads();
    for (int d = 1; d < 256; d <<= 1) {
        int v = (t >= d) ? sm[t - d] : 0;
        __syncthreads();
        sm[t] += v;
        __syncthreads();
    }
    if (t < NBKT) {
        int ex = (t == 0) ? 0 : sm[t - 1];
        bbase[t] = ex;
        bfill[t] = ex;
    }
    if (t == 0) {
        bbase[NBKT] = sm[255];       // = E
        off[n] = sm[255];
    }
}

// Radix-partition edges by dst bucket. LDS histogram -> one global atomicAdd
// per (block,bucket) -> LDS-rank -> writes are contiguous runs per bucket.
__global__ __launch_bounds__(256) void partition_kernel(const int* __restrict__ src,
                                                        const int* __restrict__ dst,
                                                        int* __restrict__ bfill,
                                                        int2* __restrict__ ebuck, int E) {
    __shared__ int lh[NBKT];
    __shared__ int lbase[NBKT];
    int t = threadIdx.x;
    int base = blockIdx.x * CHUNK_E;
    for (int i = t; i < NBKT; i += 256) lh[i] = 0;
    __syncthreads();

    int s[16], d[16], bk[16];
#pragma unroll
    for (int k = 0; k < 16; ++k) {
        int e = base + k * 256 + t;
        if (e < E) {
            s[k] = src[e];
            d[k] = dst[e];
            bk[k] = d[k] >> BSHIFT;
            atomicAdd(&lh[bk[k]], 1);
        } else {
            bk[k] = -1;
        }
    }
    __syncthreads();
    for (int i = t; i < NBKT; i += 256) {
        int c = lh[i];
        lbase[i] = c ? atomicAdd(&bfill[i], c) : 0;
        lh[i] = 0;
    }
    __syncthreads();
#pragma unroll
    for (int k = 0; k < 16; ++k) {
        if (bk[k] >= 0) {
            int r = atomicAdd(&lh[bk[k]], 1);
            ebuck[lbase[bk[k]] + r] = make_int2(s[k], d[k]);
        }
    }
}

// One block per bucket: LDS 512-bin node histogram -> LDS scan -> off[] write,
// then rank each edge via LDS atomicAdd and store esrc at its final CSR slot.
__global__ __launch_bounds__(256) void bucket_csr_kernel(const int2* __restrict__ ebuck,
                                                         const int* __restrict__ bbase,
                                                         int* __restrict__ off,
                                                         int* __restrict__ esrc, int n) {
    __shared__ int cnt[512];
    __shared__ int loff[512];
    __shared__ int sm[256];
    int b = blockIdx.x;
    int t = threadIdx.x;
    int ebeg = bbase[b];
    int eend = bbase[b + 1];
    int nbeg = b << BSHIFT;
    int nloc = n - nbeg; if (nloc > 512) nloc = 512;

    cnt[t] = 0; cnt[t + 256] = 0;
    __syncthreads();
    for (int e = ebeg + t; e < eend; e += 256) {
        atomicAdd(&cnt[ebuck[e].y - nbeg], 1);
    }
    __syncthreads();
    // exclusive scan of 512 counts (2 per thread)
    int c0 = cnt[2 * t], c1 = cnt[2 * t + 1];
    sm[t] = c0 + c1;
    __syncthreads();
    for (int d = 1; d < 256; d <<= 1) {
        int v = (t >= d) ? sm[t - d] : 0;
        __syncthreads();
        sm[t] += v;
        __syncthreads();
    }
    int basep = (t == 0) ? 0 : sm[t - 1];
    loff[2 * t] = basep;
    loff[2 * t + 1] = basep + c0;
    // reuse cnt as rank counters
    cnt[2 * t] = 0; cnt[2 * t + 1] = 0;
    __syncthreads();
    // write global off for this bucket's nodes
    for (int i = t; i < nloc; i += 256) off[nbeg + i] = ebeg + loff[i];
    // rank + final scatter (writes stay inside this bucket's esrc window)
    for (int e = ebeg + t; e < eend; e += 256) {
        int2 sd = ebuck[e];
        int d = sd.y - nbeg;
        int r = atomicAdd(&cnt[d], 1);
        esrc[ebeg + loff[d] + r] = sd.x;
    }
}

// ---------------------------------------------------------------------------
// Tiled GEMM + fused attention logits (round-4/5 structure, the only gemm
// config measured fast end-to-end): 256 threads, 128-node tile, x-tile +
// zero-padded W staged in LDS, thread (f4 = t&15, ng = t>>4 in [0,16))
// computes 4 features x 8 rows in registers. Epilogue additionally writes
// an fp16 copy h16 for the gather path (read ~17x per row).
// ---------------------------------------------------------------------------
template <int FIN, int FINP, int XSTR>
__global__ __launch_bounds__(256) void gemm_tile_kernel(
        const float* __restrict__ act, const float* __restrict__ W,
        const float* __restrict__ a_s, const float* __restrict__ a_d,
        float* __restrict__ h, __half* __restrict__ h16,
        float* __restrict__ ls, float* __restrict__ ld,
        int n) {
    __shared__ float sx[128 * XSTR];
    __shared__ float sw[FINP * 64];
    int t = threadIdx.x;
    int tb = blockIdx.x * 128;
    int nrow = n - tb; if (nrow > 128) nrow = 128;

    // stage W, zero-padded for k in [FIN, FINP)
    {
        const float4* Wv = (const float4*)W;
        float4* swv = (float4*)sw;
        for (int i = t; i < FINP * 16; i += 256) {
            int k = i >> 4;
            swv[i] = (k < FIN) ? Wv[i] : make_float4(0.0f, 0.0f, 0.0f, 0.0f);
        }
    }
    // stage x tile
    if (FIN == 64) {
        for (int i = t; i < 128 * 16; i += 256) {
            int r = i >> 4, c4 = i & 15;
            float4 v = make_float4(0.0f, 0.0f, 0.0f, 0.0f);
            if (r < nrow) v = *(const float4*)(act + (size_t)(tb + r) * 64 + c4 * 4);
            *(float4*)(sx + r * XSTR + c4 * 4) = v;
        }
    } else {
        // scalar staging for unaligned 14-float rows; pad cols [FIN,FINP) to 0
        int c = t & 15;
        for (int r = t >> 4; r < 128; r += 16) {
            float v = 0.0f;
            if (r < nrow && c < FIN) v = act[(size_t)(tb + r) * FIN + c];
            sx[r * XSTR + c] = v;
        }
    }
    __syncthreads();

    int f4 = t & 15;
    int ng = t >> 4;          // [0, 16)

    float4 acc[8];
#pragma unroll
    for (int i = 0; i < 8; ++i) acc[i] = make_float4(0.0f, 0.0f, 0.0f, 0.0f);

    for (int k4 = 0; k4 < FINP; k4 += 4) {
        float4 w0 = *(const float4*)(sw + (k4 + 0) * 64 + f4 * 4);
        float4 w1 = *(const float4*)(sw + (k4 + 1) * 64 + f4 * 4);
        float4 w2 = *(const float4*)(sw + (k4 + 2) * 64 + f4 * 4);
        float4 w3 = *(const float4*)(sw + (k4 + 3) * 64 + f4 * 4);
#pragma unroll
        for (int i = 0; i < 8; ++i) {
            float4 xv = *(const float4*)(sx + (ng + 16 * i) * XSTR + k4);
            acc[i].x = fmaf(xv.x, w0.x, acc[i].x);
            acc[i].y = fmaf(xv.x, w0.y, acc[i].y);
            acc[i].z = fmaf(xv.x, w0.z, acc[i].z);
            acc[i].w = fmaf(xv.x, w0.w, acc[i].w);
            acc[i].x = fmaf(xv.y, w1.x, acc[i].x);
            acc[i].y = fmaf(xv.y, w1.y, acc[i].y);
            acc[i].z = fmaf(xv.y, w1.z, acc[i].z);
            acc[i].w = fmaf(xv.y, w1.w, acc[i].w);
            acc[i].x = fmaf(xv.z, w2.x, acc[i].x);
            acc[i].y = fmaf(xv.z, w2.y, acc[i].y);
            acc[i].z = fmaf(xv.z, w2.z, acc[i].z);
            acc[i].w = fmaf(xv.z, w2.w, acc[i].w);
            acc[i].x = fmaf(xv.w, w3.x, acc[i].x);
            acc[i].y = fmaf(xv.w, w3.y, acc[i].y);
            acc[i].z = fmaf(xv.w, w3.z, acc[i].z);
            acc[i].w = fmaf(xv.w, w3.w, acc[i].w);
        }
    }

    float4 as4 = *(const float4*)(a_s + f4 * 4);
    float4 ad4 = *(const float4*)(a_d + f4 * 4);
#pragma unroll
    for (int i = 0; i < 8; ++i) {
        int r = ng + 16 * i;
        if (r < nrow) {                       // uniform within the 16-lane group
            int node = tb + r;
            *(float4*)(h + (size_t)node * 64 + f4 * 4) = acc[i];
            // fp16 copy for the gather path (8B per thread, 128B/row coalesced)
            __half2 plo = __floats2half2_rn(acc[i].x, acc[i].y);
            __half2 phi = __floats2half2_rn(acc[i].z, acc[i].w);
            uint2 pk;
            pk.x = *reinterpret_cast<unsigned*>(&plo);
            pk.y = *reinterpret_cast<unsigned*>(&phi);
            *reinterpret_cast<uint2*>(h16 + (size_t)node * 64 + f4 * 4) = pk;
            float vs = acc[i].x * as4.x + acc[i].y * as4.y +
                       acc[i].z * as4.z + acc[i].w * as4.w;
            float vd = acc[i].x * ad4.x + acc[i].y * ad4.y +
                       acc[i].z * ad4.z + acc[i].w * ad4.w;
            vs += __shfl_xor(vs, 1, 64); vd += __shfl_xor(vd, 1, 64);
            vs += __shfl_xor(vs, 2, 64); vd += __shfl_xor(vd, 2, 64);
            vs += __shfl_xor(vs, 4, 64); vd += __shfl_xor(vd, 4, 64);
            vs += __shfl_xor(vs, 8, 64); vd += __shfl_xor(vd, 8, 64);
            if (f4 == 0) { ls[node] = vs; ld[node] = vd; }
        }
    }
}

// ---------------------------------------------------------------------------
// GAT aggregation (round-5 v3 structure, measured best: 64.5us fp32), with
// the neighbor-row gather moved to fp16 (128B/row) while everything else
// (logits, self row, den, accumulation, output) stays fp32.
// ---------------------------------------------------------------------------
__global__ __launch_bounds__(256) void gat_aggregate_kernel(
        const float* __restrict__ h, const __half* __restrict__ h16,
        const float* __restrict__ ls,
        const float* __restrict__ ld, const int* __restrict__ off,
        const int* __restrict__ esrc, const float* __restrict__ bias,
        float* __restrict__ hout, int n) {
    __shared__ int2 smq[16 * DEG_CAP];       // .x = src, .y = ls bits then p bits
    int t = threadIdx.x;
    int fl = t & 15;
    int g = t >> 4;
    int node = blockIdx.x * 16 + g;
    if (node >= n) return;
    int2* sq = smq + g * DEG_CAP;
    int fl4 = fl * 4;

    int jb = off[node];
    int je = off[node + 1];
    int deg = je - jb;
    int degc = (deg < DEG_CAP) ? deg : DEG_CAP;
    float ldv = ld[node];
    float lself = ls[node];

    // pass 1: gather ls, stage, running max of raw ls (leaky is monotone)
    float mm = lself;
    for (int c = fl; c < degc; c += 16) {
        int s = esrc[jb + c];
        float v = ls[s];
        sq[c] = make_int2(s, __float_as_int(v));
        mm = fmaxf(mm, v);
    }
    for (int c = degc + fl; c < deg; c += 16) {        // overflow: max only
        mm = fmaxf(mm, ls[esrc[jb + c]]);
    }
    mm = fmaxf(mm, __shfl_xor(mm, 8, 64));
    mm = fmaxf(mm, __shfl_xor(mm, 4, 64));
    mm = fmaxf(mm, __shfl_xor(mm, 2, 64));
    mm = fmaxf(mm, __shfl_xor(mm, 1, 64));
    float mraw = mm + ldv;
    float m = (mraw >= 0.0f) ? mraw : NEG_SLOPE * mraw;

    // pass 2: lsv -> p in LDS, lane-partial den
    float denl = 0.0f;
    for (int c = fl; c < degc; c += 16) {
        float e = __int_as_float(sq[c].y) + ldv;
        e = (e >= 0.0f) ? e : NEG_SLOPE * e;
        float p = __expf(e - m);
        sq[c].y = __float_as_int(p);
        denl += p;
    }
    // pad to multiple of 4 with (self, p=0): exact no-op, row is cache-hot
    int degc4 = (degc + 3) & ~3;
    if (fl < degc4 - degc) sq[degc + fl] = make_int2(node, 0);

    denl += __shfl_xor(denl, 8, 64);
    denl += __shfl_xor(denl, 4, 64);
    denl += __shfl_xor(denl, 2, 64);
    denl += __shfl_xor(denl, 1, 64);

    // self row early (independent, fp32, L2-hot)
    const float4 hs = *(const float4*)(h + (size_t)node * 64 + fl4);

    // gather loop: 4 independent 128B fp16 row loads in flight per group
    float4 acc = make_float4(0.0f, 0.0f, 0.0f, 0.0f);
    for (int c = 0; c < degc4; c += 4) {
        int2 e0 = sq[c + 0];
        int2 e1 = sq[c + 1];
        int2 e2 = sq[c + 2];
        int2 e3 = sq[c + 3];
        uint2 q0 = *reinterpret_cast<const uint2*>(h16 + (size_t)e0.x * 64 + fl4);
        uint2 q1 = *reinterpret_cast<const uint2*>(h16 + (size_t)e1.x * 64 + fl4);
        uint2 q2 = *reinterpret_cast<const uint2*>(h16 + (size_t)e2.x * 64 + fl4);
        uint2 q3 = *reinterpret_cast<const uint2*>(h16 + (size_t)e3.x * 64 + fl4);
        float p0 = __int_as_float(e0.y), p1 = __int_as_float(e1.y);
        float p2 = __int_as_float(e2.y), p3 = __int_as_float(e3.y);
        float2 a0 = __half22float2(*reinterpret_cast<__half2*>(&q0.x));
        float2 b0 = __half22float2(*reinterpret_cast<__half2*>(&q0.y));
        float2 a1 = __half22float2(*reinterpret_cast<__half2*>(&q1.x));
        float2 b1 = __half22float2(*reinterpret_cast<__half2*>(&q1.y));
        float2 a2 = __half22float2(*reinterpret_cast<__half2*>(&q2.x));
        float2 b2 = __half22float2(*reinterpret_cast<__half2*>(&q2.y));
        float2 a3 = __half22float2(*reinterpret_cast<__half2*>(&q3.x));
        float2 b3 = __half22float2(*reinterpret_cast<__half2*>(&q3.y));
        acc.x = fmaf(p0, a0.x, acc.x); acc.y = fmaf(p0, a0.y, acc.y);
        acc.z = fmaf(p0, b0.x, acc.z); acc.w = fmaf(p0, b0.y, acc.w);
        acc.x = fmaf(p1, a1.x, acc.x); acc.y = fmaf(p1, a1.y, acc.y);
        acc.z = fmaf(p1, b1.x, acc.z); acc.w = fmaf(p1, b1.y, acc.w);
        acc.x = fmaf(p2, a2.x, acc.x); acc.y = fmaf(p2, a2.y, acc.y);
        acc.z = fmaf(p2, b2.x, acc.z); acc.w = fmaf(p2, b2.y, acc.w);
        acc.x = fmaf(p3, a3.x, acc.x); acc.y = fmaf(p3, a3.y, acc.y);
        acc.z = fmaf(p3, b3.x, acc.z); acc.w = fmaf(p3, b3.y, acc.w);
    }

    // overflow tail (deg > DEG_CAP, ~never): serial, fp32 rows
    float den_of = 0.0f;
    for (int j = jb + DEG_CAP; j < je; ++j) {
        int s = esrc[j];
        float e = ls[s] + ldv;
        e = (e >= 0.0f) ? e : NEG_SLOPE * e;
        float p = __expf(e - m);
        den_of += p;
        const float4 hv = *(const float4*)(h + (size_t)s * 64 + fl4);
        acc.x = fmaf(p, hv.x, acc.x);
        acc.y = fmaf(p, hv.y, acc.y);
        acc.z = fmaf(p, hv.z, acc.z);
        acc.w = fmaf(p, hv.w, acc.w);
    }

    // self loop (fp32, exact)
    float e0s = lself + ldv;
    e0s = (e0s >= 0.0f) ? e0s : NEG_SLOPE * e0s;
    float p0s = __expf(e0s - m);
    float den = denl + den_of + p0s;
    acc.x = fmaf(p0s, hs.x, acc.x);
    acc.y = fmaf(p0s, hs.y, acc.y);
    acc.z = fmaf(p0s, hs.z, acc.z);
    acc.w = fmaf(p0s, hs.w, acc.w);

    const float4 b4 = *(const float4*)(bias + fl4);
    float inv = 1.0f / den;
    float4 o;
    o.x = acc.x * inv + b4.x;
    o.y = acc.y * inv + b4.y;
    o.z = acc.z * inv + b4.z;
    o.w = acc.w * inv + b4.w;
    o.x = (o.x > 0.0f) ? o.x : expm1f(o.x);
    o.y = (o.y > 0.0f) ? o.y : expm1f(o.y);
    o.z = (o.z > 0.0f) ? o.z : expm1f(o.z);
    o.w = (o.w > 0.0f) ? o.w : expm1f(o.w);
    *(float4*)(hout + (size_t)node * 64 + fl4) = o;
}

// ---------------------------------------------------------------------------
// Global max pool: run-length (batch is sorted) + encoded atomicMax
// ---------------------------------------------------------------------------
__device__ __forceinline__ unsigned enc_f32(float f) {
    unsigned b = __float_as_uint(f);
    return (b & 0x80000000u) ? ~b : (b | 0x80000000u);
}

__global__ __launch_bounds__(256) void pool_kernel(const float* __restrict__ h,
                                                   const int* __restrict__ batch,
                                                   unsigned* __restrict__ genc, int n) {
    int lane = threadIdx.x & 63;
    int w = blockIdx.x * 4 + (threadIdx.x >> 6);
    int start = w * 64;
    if (start >= n) return;
    int end = start + 64; if (end > n) end = n;
    int cur = batch[start];
    float rm = -1e38f;
    for (int node = start; node < end; ++node) {
        int b = batch[node];                     // wave-uniform
        if (b != cur) {
            atomicMax(&genc[cur * 64 + lane], enc_f32(rm));
            cur = b;
            rm = -1e38f;
        }
        rm = fmaxf(rm, h[(size_t)node * 64 + lane]);
    }
    atomicMax(&genc[cur * 64 + lane], enc_f32(rm));
}

__global__ __launch_bounds__(64) void final_kernel(const unsigned* __restrict__ genc,
                                                   const float* __restrict__ linW,
                                                   const float* __restrict__ linb,
                                                   float* __restrict__ out) {
    int g = blockIdx.x;
    int lane = threadIdx.x;
    unsigned u = genc[g * 64 + lane];
    float v;
    if (u == 0u) {
        v = 0.0f;
    } else {
        unsigned b = (u & 0x80000000u) ? (u ^ 0x80000000u) : ~u;
        v = __uint_as_float(b);
    }
    float c0 = v * linW[lane * 2 + 0];
    float c1 = v * linW[lane * 2 + 1];
#pragma unroll
    for (int d = 32; d >= 1; d >>= 1) {
        c0 += __shfl_xor(c0, d, 64);
        c1 += __shfl_xor(c1, d, 64);
    }
    if (lane == 0) {
        out[g * 2 + 0] = c0 + linb[0];
        out[g * 2 + 1] = c1 + linb[1];
    }
}

// ---------------------------------------------------------------------------
// Launch
// ---------------------------------------------------------------------------
static inline size_t align_up(size_t v, size_t a) { return (v + a - 1) & ~(a - 1); }

extern "C" void kernel_launch(void* const* d_in, const int* in_sizes, int n_in,
                              void* d_out, int out_size, void* d_ws, size_t ws_size,
                              hipStream_t stream) {
    const float* x          = (const float*)d_in[0];
    const int*   edge_index = (const int*)d_in[1];
    const int*   batch      = (const int*)d_in[2];
    const float* W[5];
    const float* a_s[5];
    const float* a_d[5];
    const float* bias[5];
    for (int l = 0; l < 5; ++l) {
        W[l]    = (const float*)d_in[3 + 4 * l + 0];
        a_s[l]  = (const float*)d_in[3 + 4 * l + 1];
        a_d[l]  = (const float*)d_in[3 + 4 * l + 2];
        bias[l] = (const float*)d_in[3 + 4 * l + 3];
    }
    const float* linW = (const float*)d_in[23];
    const float* linb = (const float*)d_in[24];
    float* out = (float*)d_out;

    const int N = N_NODES;
    const int E = in_sizes[1] / 2;
    const int* srcp = edge_index;
    const int* dstp = edge_index + E;

    // workspace partition
    char* p = (char*)d_ws;
    int* bcount = (int*)p;        p += align_up((size_t)NBKT * 4, 256);
    int* bbase  = (int*)p;        p += align_up((size_t)(NBKT + 1) * 4, 256);
    int* bfill  = (int*)p;        p += align_up((size_t)NBKT * 4, 256);
    int* off    = (int*)p;        p += align_up((size_t)(N + 1) * 4, 256);
    int* esrc   = (int*)p;        p += align_up((size_t)E * 4, 256);
    float* lsb  = (float*)p;      p += align_up((size_t)N * 4, 256);
    float* ldb  = (float*)p;      p += align_up((size_t)N * 4, 256);
    float* h_a  = (float*)p;      p += align_up((size_t)N * 64 * 4, 256);
    float* h_b  = (float*)p;      p += align_up((size_t)N * 64 * 4, 256);
    __half* h16 = (__half*)p;     p += align_up((size_t)N * 64 * 2, 256);
    unsigned* genc = (unsigned*)p; p += align_up((size_t)G_GRAPHS * 64 * 4, 256);

    // ebuck (E int2 = 12.8MB) aliases h_b (25.6MB): fully consumed by
    // bucket_csr before the first gemm writes h_b.
    int2* ebuck = (int2*)h_b;

    hipMemsetAsync(bcount, 0, (size_t)NBKT * 4, stream);
    hipMemsetAsync(genc, 0, (size_t)G_GRAPHS * 64 * 4, stream);

    int pb2 = (E + CHUNK_E - 1) / CHUNK_E;
    bucket_hist_kernel<<<pb2, 256, 0, stream>>>(dstp, bcount, E);
    bucket_scan_kernel<<<1, 256, 0, stream>>>(bcount, bbase, bfill, off, N);
    partition_kernel<<<pb2, 256, 0, stream>>>(srcp, dstp, bfill, ebuck, E);
    bucket_csr_kernel<<<NBKT, 256, 0, stream>>>(ebuck, bbase, off, esrc, N);

    int nb = (N + 15) / 16;   // 16 nodes per block (16-lane group per node)
    int gt = (N + 127) / 128; // GEMM: 128-node tiles, 256 threads
    gemm_tile_kernel<14, 16, 20><<<gt, 256, 0, stream>>>(x, W[0], a_s[0], a_d[0],
                                                         h_b, h16, lsb, ldb, N);
    gat_aggregate_kernel<<<nb, 256, 0, stream>>>(h_b, h16, lsb, ldb, off, esrc,
                                                 bias[0], h_a, N);
    for (int l = 1; l < 5; ++l) {
        gemm_tile_kernel<64, 64, 68><<<gt, 256, 0, stream>>>(h_a, W[l], a_s[l], a_d[l],
                                                             h_b, h16, lsb, ldb, N);
        gat_aggregate_kernel<<<nb, 256, 0, stream>>>(h_b, h16, lsb, ldb, off, esrc,
                                                     bias[l], h_a, N);
    }

    int pw = (N + 63) / 64;
    int pbk = (pw + 3) / 4;
    pool_kernel<<<pbk, 256, 0, stream>>>(h_a, batch, genc, N);
    final_kernel<<<G_GRAPHS, 64, 0, stream>>>(genc, linW, linb, out);
}

// Round 11
// 488.632 us; speedup vs baseline: 1.4697x; 1.0540x over previous
//
#include <hip/hip_runtime.h>
#include <hip/hip_fp16.h>
#include <math.h>

#define N_NODES 100000
#define H_DIM 64
#define G_GRAPHS 512
#define NEG_SLOPE 0.2f

// bucketed CSR-build params
#define BSHIFT 9                         // 512 nodes per bucket
#define NBKT ((N_NODES + (1 << BSHIFT) - 1) >> BSHIFT)   // 196
#define CHUNK_E 4096                     // edges per partition block (16/thread)

#define DEG_CAP 128                      // staged edges per node (Poisson(16) max ~45)

// packed edge: src in bits [0,17), in-bucket dst in bits [17,26)
#define PK_SRC(v)  ((v) & 0x1FFFF)
#define PK_LD(v)   ((v) >> 17)

// ---------------------------------------------------------------------------
// CSR build, bucket-first: no per-edge global atomics anywhere.
// ---------------------------------------------------------------------------

// 196-bin LDS histogram -> 196 global atomics per block
__global__ __launch_bounds__(256) void bucket_hist_kernel(const int* __restrict__ dst,
                                                          int* __restrict__ bcount, int E) {
    __shared__ int lh[NBKT];
    int t = threadIdx.x;
    for (int i = t; i < NBKT; i += 256) lh[i] = 0;
    __syncthreads();
    int base = blockIdx.x * CHUNK_E;
#pragma unroll
    for (int k = 0; k < 16; ++k) {
        int e = base + k * 256 + t;
        if (e < E) atomicAdd(&lh[dst[e] >> BSHIFT], 1);
    }
    __syncthreads();
    for (int i = t; i < NBKT; i += 256) {
        int c = lh[i];
        if (c) atomicAdd(&bcount[i], c);
    }
}

// single block: exclusive scan of 196 bucket counts -> bbase[0..NBKT], bfill copy
__global__ __launch_bounds__(256) void bucket_scan_kernel(const int* __restrict__ bcount,
                                                          int* __restrict__ bbase,
                                                          int* __restrict__ bfill,
                                                          int* __restrict__ off, int n) {
    __shared__ int sm[256];
    int t = threadIdx.x;
    sm[t] = (t < NBKT) ? bcount[t] : 0;
    __syncthreads();
    for (int d = 1; d < 256; d <<= 1) {
        int v = (t >= d) ? sm[t - d] : 0;
        __syncthreads();
        sm[t] += v;
        __syncthreads();
    }
    if (t < NBKT) {
        int ex = (t == 0) ? 0 : sm[t - 1];
        bbase[t] = ex;
        bfill[t] = ex;
    }
    if (t == 0) {
        bbase[NBKT] = sm[255];       // = E
        off[n] = sm[255];
    }
}

// Radix-partition edges by dst bucket. LDS histogram -> one global atomicAdd
// per (block,bucket) -> LDS-rank -> writes are contiguous runs per bucket.
// Edges stored packed (4B): src | local_dst<<17.
__global__ __launch_bounds__(256) void partition_kernel(const int* __restrict__ src,
                                                        const int* __restrict__ dst,
                                                        int* __restrict__ bfill,
                                                        int* __restrict__ ebuck, int E) {
    __shared__ int lh[NBKT];
    __shared__ int lbase[NBKT];
    int t = threadIdx.x;
    int base = blockIdx.x * CHUNK_E;
    for (int i = t; i < NBKT; i += 256) lh[i] = 0;
    __syncthreads();

    int pk[16], bk[16];
#pragma unroll
    for (int k = 0; k < 16; ++k) {
        int e = base + k * 256 + t;
        if (e < E) {
            int s = src[e];
            int d = dst[e];
            bk[k] = d >> BSHIFT;
            pk[k] = s | ((d & ((1 << BSHIFT) - 1)) << 17);
            atomicAdd(&lh[bk[k]], 1);
        } else {
            bk[k] = -1;
        }
    }
    __syncthreads();
    for (int i = t; i < NBKT; i += 256) {
        int c = lh[i];
        lbase[i] = c ? atomicAdd(&bfill[i], c) : 0;
        lh[i] = 0;
    }
    __syncthreads();
#pragma unroll
    for (int k = 0; k < 16; ++k) {
        if (bk[k] >= 0) {
            int r = atomicAdd(&lh[bk[k]], 1);
            ebuck[lbase[bk[k]] + r] = pk[k];
        }
    }
}

// One block per bucket: LDS 512-bin node histogram -> LDS scan -> off[] write,
// then rank each edge via LDS atomicAdd and store esrc at its final CSR slot.
__global__ __launch_bounds__(256) void bucket_csr_kernel(const int* __restrict__ ebuck,
                                                         const int* __restrict__ bbase,
                                                         int* __restrict__ off,
                                                         int* __restrict__ esrc, int n) {
    __shared__ int cnt[512];
    __shared__ int loff[512];
    __shared__ int sm[256];
    int b = blockIdx.x;
    int t = threadIdx.x;
    int ebeg = bbase[b];
    int eend = bbase[b + 1];
    int nbeg = b << BSHIFT;
    int nloc = n - nbeg; if (nloc > 512) nloc = 512;

    cnt[t] = 0; cnt[t + 256] = 0;
    __syncthreads();
    for (int e = ebeg + t; e < eend; e += 256) {
        atomicAdd(&cnt[PK_LD(ebuck[e])], 1);
    }
    __syncthreads();
    // exclusive scan of 512 counts (2 per thread)
    int c0 = cnt[2 * t], c1 = cnt[2 * t + 1];
    sm[t] = c0 + c1;
    __syncthreads();
    for (int d = 1; d < 256; d <<= 1) {
        int v = (t >= d) ? sm[t - d] : 0;
        __syncthreads();
        sm[t] += v;
        __syncthreads();
    }
    int basep = (t == 0) ? 0 : sm[t - 1];
    loff[2 * t] = basep;
    loff[2 * t + 1] = basep + c0;
    // reuse cnt as rank counters
    cnt[2 * t] = 0; cnt[2 * t + 1] = 0;
    __syncthreads();
    // write global off for this bucket's nodes
    for (int i = t; i < nloc; i += 256) off[nbeg + i] = ebeg + loff[i];
    // rank + final scatter (writes stay inside this bucket's esrc window)
    for (int e = ebeg + t; e < eend; e += 256) {
        int v = ebuck[e];
        int d = PK_LD(v);
        int r = atomicAdd(&cnt[d], 1);
        esrc[ebeg + loff[d] + r] = PK_SRC(v);
    }
}

// ---------------------------------------------------------------------------
// Tiled GEMM + fused attention logits (round-4/5 structure): 256 threads,
// 128-node tile, x-tile + zero-padded W staged in LDS, thread (f4 = t&15,
// ng = t>>4 in [0,16)) computes 4 features x 8 rows in registers.
// Output is fp16-only (h16): the gather path reads it ~17x/row, the self-row
// once; fp32 h is never needed downstream -> saves 26MB writes per layer.
// ---------------------------------------------------------------------------
template <int FIN, int FINP, int XSTR>
__global__ __launch_bounds__(256) void gemm_tile_kernel(
        const float* __restrict__ act, const float* __restrict__ W,
        const float* __restrict__ a_s, const float* __restrict__ a_d,
        __half* __restrict__ h16,
        float* __restrict__ ls, float* __restrict__ ld,
        int n) {
    __shared__ float sx[128 * XSTR];
    __shared__ float sw[FINP * 64];
    int t = threadIdx.x;
    int tb = blockIdx.x * 128;
    int nrow = n - tb; if (nrow > 128) nrow = 128;

    // stage W, zero-padded for k in [FIN, FINP)
    {
        const float4* Wv = (const float4*)W;
        float4* swv = (float4*)sw;
        for (int i = t; i < FINP * 16; i += 256) {
            int k = i >> 4;
            swv[i] = (k < FIN) ? Wv[i] : make_float4(0.0f, 0.0f, 0.0f, 0.0f);
        }
    }
    // stage x tile
    if (FIN == 64) {
        for (int i = t; i < 128 * 16; i += 256) {
            int r = i >> 4, c4 = i & 15;
            float4 v = make_float4(0.0f, 0.0f, 0.0f, 0.0f);
            if (r < nrow) v = *(const float4*)(act + (size_t)(tb + r) * 64 + c4 * 4);
            *(float4*)(sx + r * XSTR + c4 * 4) = v;
        }
    } else {
        // scalar staging for unaligned 14-float rows; pad cols [FIN,FINP) to 0
        int c = t & 15;
        for (int r = t >> 4; r < 128; r += 16) {
            float v = 0.0f;
            if (r < nrow && c < FIN) v = act[(size_t)(tb + r) * FIN + c];
            sx[r * XSTR + c] = v;
        }
    }
    __syncthreads();

    int f4 = t & 15;
    int ng = t >> 4;          // [0, 16)

    float4 acc[8];
#pragma unroll
    for (int i = 0; i < 8; ++i) acc[i] = make_float4(0.0f, 0.0f, 0.0f, 0.0f);

    for (int k4 = 0; k4 < FINP; k4 += 4) {
        float4 w0 = *(const float4*)(sw + (k4 + 0) * 64 + f4 * 4);
        float4 w1 = *(const float4*)(sw + (k4 + 1) * 64 + f4 * 4);
        float4 w2 = *(const float4*)(sw + (k4 + 2) * 64 + f4 * 4);
        float4 w3 = *(const float4*)(sw + (k4 + 3) * 64 + f4 * 4);
#pragma unroll
        for (int i = 0; i < 8; ++i) {
            float4 xv = *(const float4*)(sx + (ng + 16 * i) * XSTR + k4);
            acc[i].x = fmaf(xv.x, w0.x, acc[i].x);
            acc[i].y = fmaf(xv.x, w0.y, acc[i].y);
            acc[i].z = fmaf(xv.x, w0.z, acc[i].z);
            acc[i].w = fmaf(xv.x, w0.w, acc[i].w);
            acc[i].x = fmaf(xv.y, w1.x, acc[i].x);
            acc[i].y = fmaf(xv.y, w1.y, acc[i].y);
            acc[i].z = fmaf(xv.y, w1.z, acc[i].z);
            acc[i].w = fmaf(xv.y, w1.w, acc[i].w);
            acc[i].x = fmaf(xv.z, w2.x, acc[i].x);
            acc[i].y = fmaf(xv.z, w2.y, acc[i].y);
            acc[i].z = fmaf(xv.z, w2.z, acc[i].z);
            acc[i].w = fmaf(xv.z, w2.w, acc[i].w);
            acc[i].x = fmaf(xv.w, w3.x, acc[i].x);
            acc[i].y = fmaf(xv.w, w3.y, acc[i].y);
            acc[i].z = fmaf(xv.w, w3.z, acc[i].z);
            acc[i].w = fmaf(xv.w, w3.w, acc[i].w);
        }
    }

    float4 as4 = *(const float4*)(a_s + f4 * 4);
    float4 ad4 = *(const float4*)(a_d + f4 * 4);
#pragma unroll
    for (int i = 0; i < 8; ++i) {
        int r = ng + 16 * i;
        if (r < nrow) {                       // uniform within the 16-lane group
            int node = tb + r;
            __half2 plo = __floats2half2_rn(acc[i].x, acc[i].y);
            __half2 phi = __floats2half2_rn(acc[i].z, acc[i].w);
            uint2 pk;
            pk.x = *reinterpret_cast<unsigned*>(&plo);
            pk.y = *reinterpret_cast<unsigned*>(&phi);
            *reinterpret_cast<uint2*>(h16 + (size_t)node * 64 + f4 * 4) = pk;
            float vs = acc[i].x * as4.x + acc[i].y * as4.y +
                       acc[i].z * as4.z + acc[i].w * as4.w;
            float vd = acc[i].x * ad4.x + acc[i].y * ad4.y +
                       acc[i].z * ad4.z + acc[i].w * ad4.w;
            vs += __shfl_xor(vs, 1, 64); vd += __shfl_xor(vd, 1, 64);
            vs += __shfl_xor(vs, 2, 64); vd += __shfl_xor(vd, 2, 64);
            vs += __shfl_xor(vs, 4, 64); vd += __shfl_xor(vd, 4, 64);
            vs += __shfl_xor(vs, 8, 64); vd += __shfl_xor(vd, 8, 64);
            if (f4 == 0) { ls[node] = vs; ld[node] = vd; }
        }
    }
}

// ---------------------------------------------------------------------------
// GAT aggregation (round-5 v3 structure): 16-lane group per node, LDS-staged
// (src,p) pairs, 4-wide gather. All h-rows (neighbors AND self) read fp16;
// logits/den/accumulation/output stay fp32.
// ---------------------------------------------------------------------------
__global__ __launch_bounds__(256) void gat_aggregate_kernel(
        const __half* __restrict__ h16,
        const float* __restrict__ ls,
        const float* __restrict__ ld, const int* __restrict__ off,
        const int* __restrict__ esrc, const float* __restrict__ bias,
        float* __restrict__ hout, int n) {
    __shared__ int2 smq[16 * DEG_CAP];       // .x = src, .y = ls bits then p bits
    int t = threadIdx.x;
    int fl = t & 15;
    int g = t >> 4;
    int node = blockIdx.x * 16 + g;
    if (node >= n) return;
    int2* sq = smq + g * DEG_CAP;
    int fl4 = fl * 4;

    int jb = off[node];
    int je = off[node + 1];
    int deg = je - jb;
    int degc = (deg < DEG_CAP) ? deg : DEG_CAP;
    float ldv = ld[node];
    float lself = ls[node];

    // pass 1: gather ls, stage, running max of raw ls (leaky is monotone)
    float mm = lself;
    for (int c = fl; c < degc; c += 16) {
        int s = esrc[jb + c];
        float v = ls[s];
        sq[c] = make_int2(s, __float_as_int(v));
        mm = fmaxf(mm, v);
    }
    for (int c = degc + fl; c < deg; c += 16) {        // overflow: max only
        mm = fmaxf(mm, ls[esrc[jb + c]]);
    }
    mm = fmaxf(mm, __shfl_xor(mm, 8, 64));
    mm = fmaxf(mm, __shfl_xor(mm, 4, 64));
    mm = fmaxf(mm, __shfl_xor(mm, 2, 64));
    mm = fmaxf(mm, __shfl_xor(mm, 1, 64));
    float mraw = mm + ldv;
    float m = (mraw >= 0.0f) ? mraw : NEG_SLOPE * mraw;

    // pass 2: lsv -> p in LDS, lane-partial den
    float denl = 0.0f;
    for (int c = fl; c < degc; c += 16) {
        float e = __int_as_float(sq[c].y) + ldv;
        e = (e >= 0.0f) ? e : NEG_SLOPE * e;
        float p = __expf(e - m);
        sq[c].y = __float_as_int(p);
        denl += p;
    }
    // pad to multiple of 4 with (self, p=0): exact no-op, row is cache-hot
    int degc4 = (degc + 3) & ~3;
    if (fl < degc4 - degc) sq[degc + fl] = make_int2(node, 0);

    denl += __shfl_xor(denl, 8, 64);
    denl += __shfl_xor(denl, 4, 64);
    denl += __shfl_xor(denl, 2, 64);
    denl += __shfl_xor(denl, 1, 64);

    // self row early (independent, fp16 -> fp32, cache-hot)
    uint2 qs = *reinterpret_cast<const uint2*>(h16 + (size_t)node * 64 + fl4);
    float2 sa = __half22float2(*reinterpret_cast<__half2*>(&qs.x));
    float2 sb = __half22float2(*reinterpret_cast<__half2*>(&qs.y));

    // gather loop: 4 independent 128B fp16 row loads in flight per group
    float4 acc = make_float4(0.0f, 0.0f, 0.0f, 0.0f);
    for (int c = 0; c < degc4; c += 4) {
        int2 e0 = sq[c + 0];
        int2 e1 = sq[c + 1];
        int2 e2 = sq[c + 2];
        int2 e3 = sq[c + 3];
        uint2 q0 = *reinterpret_cast<const uint2*>(h16 + (size_t)e0.x * 64 + fl4);
        uint2 q1 = *reinterpret_cast<const uint2*>(h16 + (size_t)e1.x * 64 + fl4);
        uint2 q2 = *reinterpret_cast<const uint2*>(h16 + (size_t)e2.x * 64 + fl4);
        uint2 q3 = *reinterpret_cast<const uint2*>(h16 + (size_t)e3.x * 64 + fl4);
        float p0 = __int_as_float(e0.y), p1 = __int_as_float(e1.y);
        float p2 = __int_as_float(e2.y), p3 = __int_as_float(e3.y);
        float2 a0 = __half22float2(*reinterpret_cast<__half2*>(&q0.x));
        float2 b0 = __half22float2(*reinterpret_cast<__half2*>(&q0.y));
        float2 a1 = __half22float2(*reinterpret_cast<__half2*>(&q1.x));
        float2 b1 = __half22float2(*reinterpret_cast<__half2*>(&q1.y));
        float2 a2 = __half22float2(*reinterpret_cast<__half2*>(&q2.x));
        float2 b2 = __half22float2(*reinterpret_cast<__half2*>(&q2.y));
        float2 a3 = __half22float2(*reinterpret_cast<__half2*>(&q3.x));
        float2 b3 = __half22float2(*reinterpret_cast<__half2*>(&q3.y));
        acc.x = fmaf(p0, a0.x, acc.x); acc.y = fmaf(p0, a0.y, acc.y);
        acc.z = fmaf(p0, b0.x, acc.z); acc.w = fmaf(p0, b0.y, acc.w);
        acc.x = fmaf(p1, a1.x, acc.x); acc.y = fmaf(p1, a1.y, acc.y);
        acc.z = fmaf(p1, b1.x, acc.z); acc.w = fmaf(p1, b1.y, acc.w);
        acc.x = fmaf(p2, a2.x, acc.x); acc.y = fmaf(p2, a2.y, acc.y);
        acc.z = fmaf(p2, b2.x, acc.z); acc.w = fmaf(p2, b2.y, acc.w);
        acc.x = fmaf(p3, a3.x, acc.x); acc.y = fmaf(p3, a3.y, acc.y);
        acc.z = fmaf(p3, b3.x, acc.z); acc.w = fmaf(p3, b3.y, acc.w);
    }

    // overflow tail (deg > DEG_CAP, ~never): serial, fp16 rows
    float den_of = 0.0f;
    for (int j = jb + DEG_CAP; j < je; ++j) {
        int s = esrc[j];
        float e = ls[s] + ldv;
        e = (e >= 0.0f) ? e : NEG_SLOPE * e;
        float p = __expf(e - m);
        den_of += p;
        uint2 qv = *reinterpret_cast<const uint2*>(h16 + (size_t)s * 64 + fl4);
        float2 va = __half22float2(*reinterpret_cast<__half2*>(&qv.x));
        float2 vb = __half22float2(*reinterpret_cast<__half2*>(&qv.y));
        acc.x = fmaf(p, va.x, acc.x);
        acc.y = fmaf(p, va.y, acc.y);
        acc.z = fmaf(p, vb.x, acc.z);
        acc.w = fmaf(p, vb.y, acc.w);
    }

    // self loop
    float e0s = lself + ldv;
    e0s = (e0s >= 0.0f) ? e0s : NEG_SLOPE * e0s;
    float p0s = __expf(e0s - m);
    float den = denl + den_of + p0s;
    acc.x = fmaf(p0s, sa.x, acc.x);
    acc.y = fmaf(p0s, sa.y, acc.y);
    acc.z = fmaf(p0s, sb.x, acc.z);
    acc.w = fmaf(p0s, sb.y, acc.w);

    const float4 b4 = *(const float4*)(bias + fl4);
    float inv = 1.0f / den;
    float4 o;
    o.x = acc.x * inv + b4.x;
    o.y = acc.y * inv + b4.y;
    o.z = acc.z * inv + b4.z;
    o.w = acc.w * inv + b4.w;
    o.x = (o.x > 0.0f) ? o.x : expm1f(o.x);
    o.y = (o.y > 0.0f) ? o.y : expm1f(o.y);
    o.z = (o.z > 0.0f) ? o.z : expm1f(o.z);
    o.w = (o.w > 0.0f) ? o.w : expm1f(o.w);
    *(float4*)(hout + (size_t)node * 64 + fl4) = o;
}

// ---------------------------------------------------------------------------
// Global max pool: run-length (batch is sorted) + encoded atomicMax
// ---------------------------------------------------------------------------
__device__ __forceinline__ unsigned enc_f32(float f) {
    unsigned b = __float_as_uint(f);
    return (b & 0x80000000u) ? ~b : (b | 0x80000000u);
}

__global__ __launch_bounds__(256) void pool_kernel(const float* __restrict__ h,
                                                   const int* __restrict__ batch,
                                                   unsigned* __restrict__ genc, int n) {
    int lane = threadIdx.x & 63;
    int w = blockIdx.x * 4 + (threadIdx.x >> 6);
    int start = w * 64;
    if (start >= n) return;
    int end = start + 64; if (end > n) end = n;
    int cur = batch[start];
    float rm = -1e38f;
    for (int node = start; node < end; ++node) {
        int b = batch[node];                     // wave-uniform
        if (b != cur) {
            atomicMax(&genc[cur * 64 + lane], enc_f32(rm));
            cur = b;
            rm = -1e38f;
        }
        rm = fmaxf(rm, h[(size_t)node * 64 + lane]);
    }
    atomicMax(&genc[cur * 64 + lane], enc_f32(rm));
}

__global__ __launch_bounds__(64) void final_kernel(const unsigned* __restrict__ genc,
                                                   const float* __restrict__ linW,
                                                   const float* __restrict__ linb,
                                                   float* __restrict__ out) {
    int g = blockIdx.x;
    int lane = threadIdx.x;
    unsigned u = genc[g * 64 + lane];
    float v;
    if (u == 0u) {
        v = 0.0f;
    } else {
        unsigned b = (u & 0x80000000u) ? (u ^ 0x80000000u) : ~u;
        v = __uint_as_float(b);
    }
    float c0 = v * linW[lane * 2 + 0];
    float c1 = v * linW[lane * 2 + 1];
#pragma unroll
    for (int d = 32; d >= 1; d >>= 1) {
        c0 += __shfl_xor(c0, d, 64);
        c1 += __shfl_xor(c1, d, 64);
    }
    if (lane == 0) {
        out[g * 2 + 0] = c0 + linb[0];
        out[g * 2 + 1] = c1 + linb[1];
    }
}

// ---------------------------------------------------------------------------
// Launch
// ---------------------------------------------------------------------------
static inline size_t align_up(size_t v, size_t a) { return (v + a - 1) & ~(a - 1); }

extern "C" void kernel_launch(void* const* d_in, const int* in_sizes, int n_in,
                              void* d_out, int out_size, void* d_ws, size_t ws_size,
                              hipStream_t stream) {
    const float* x          = (const float*)d_in[0];
    const int*   edge_index = (const int*)d_in[1];
    const int*   batch      = (const int*)d_in[2];
    const float* W[5];
    const float* a_s[5];
    const float* a_d[5];
    const float* bias[5];
    for (int l = 0; l < 5; ++l) {
        W[l]    = (const float*)d_in[3 + 4 * l + 0];
        a_s[l]  = (const float*)d_in[3 + 4 * l + 1];
        a_d[l]  = (const float*)d_in[3 + 4 * l + 2];
        bias[l] = (const float*)d_in[3 + 4 * l + 3];
    }
    const float* linW = (const float*)d_in[23];
    const float* linb = (const float*)d_in[24];
    float* out = (float*)d_out;

    const int N = N_NODES;
    const int E = in_sizes[1] / 2;
    const int* srcp = edge_index;
    const int* dstp = edge_index + E;

    // workspace partition
    char* p = (char*)d_ws;
    int* bcount = (int*)p;        p += align_up((size_t)NBKT * 4, 256);
    int* bbase  = (int*)p;        p += align_up((size_t)(NBKT + 1) * 4, 256);
    int* bfill  = (int*)p;        p += align_up((size_t)NBKT * 4, 256);
    int* off    = (int*)p;        p += align_up((size_t)(N + 1) * 4, 256);
    int* esrc   = (int*)p;        p += align_up((size_t)E * 4, 256);
    float* lsb  = (float*)p;      p += align_up((size_t)N * 4, 256);
    float* ldb  = (float*)p;      p += align_up((size_t)N * 4, 256);
    float* h_a  = (float*)p;      p += align_up((size_t)N * 64 * 4, 256);
    __half* h16 = (__half*)p;     p += align_up((size_t)N * 64 * 2, 256);
    unsigned* genc = (unsigned*)p; p += align_up((size_t)G_GRAPHS * 64 * 4, 256);

    // ebuck (E ints, 6.4MB, packed) aliases h_a (25.6MB): fully consumed by
    // bucket_csr before the first gat writes h_a.
    int* ebuck = (int*)h_a;

    hipMemsetAsync(bcount, 0, (size_t)NBKT * 4, stream);
    hipMemsetAsync(genc, 0, (size_t)G_GRAPHS * 64 * 4, stream);

    int pb2 = (E + CHUNK_E - 1) / CHUNK_E;
    bucket_hist_kernel<<<pb2, 256, 0, stream>>>(dstp, bcount, E);
    bucket_scan_kernel<<<1, 256, 0, stream>>>(bcount, bbase, bfill, off, N);
    partition_kernel<<<pb2, 256, 0, stream>>>(srcp, dstp, bfill, ebuck, E);
    bucket_csr_kernel<<<NBKT, 256, 0, stream>>>(ebuck, bbase, off, esrc, N);

    int nb = (N + 15) / 16;   // 16 nodes per block (16-lane group per node)
    int gt = (N + 127) / 128; // GEMM: 128-node tiles, 256 threads
    gemm_tile_kernel<14, 16, 20><<<gt, 256, 0, stream>>>(x, W[0], a_s[0], a_d[0],
                                                         h16, lsb, ldb, N);
    gat_aggregate_kernel<<<nb, 256, 0, stream>>>(h16, lsb, ldb, off, esrc,
                                                 bias[0], h_a, N);
    for (int l = 1; l < 5; ++l) {
        gemm_tile_kernel<64, 64, 68><<<gt, 256, 0, stream>>>(h_a, W[l], a_s[l], a_d[l],
                                                             h16, lsb, ldb, N);
        gat_aggregate_kernel<<<nb, 256, 0, stream>>>(h16, lsb, ldb, off, esrc,
                                                     bias[l], h_a, N);
    }

    int pw = (N + 63) / 64;
    int pbk = (pw + 3) / 4;
    pool_kernel<<<pbk, 256, 0, stream>>>(h_a, batch, genc, N);
    final_kernel<<<G_GRAPHS, 64, 0, stream>>>(genc, linW, linb, out);
}